// Round 4
// baseline (269.391 us; speedup 1.0000x reference)
//
#include <hip/hip_runtime.h>

#define NUSERS 100000
#define NITEMS 50000
#define NTOT   150000   // NUSERS + NITEMS
#define NBIC   20000
#define DIM    64

// concatenated row space: [adj rows | hv rows | hu rows]
#define HV_BASE  NTOT
#define HU_BASE  (NTOT + NBIC)
#define NROWS_ALL (NTOT + NBIC + NUSERS)   // 270000

// static region-aware buckets: ~4000 expected edges per bucket
#define ADJ_RPB  500
#define NB_ADJ   300
#define HV_RPB   200
#define NB_HV    100
#define HU_RPB   1000
#define NB_HU    100
#define NBKT     (NB_ADJ + NB_HV + NB_HU)   // 500
#define HSIZE    512

#define EDGE_CAP 5120
#define ROWS_CAP 1024
#define CHUNK    8192
#define PA_BLK   1024
#define PB_BLK   512

typedef _Float16 h8 __attribute__((ext_vector_type(8)));
typedef float    f4 __attribute__((ext_vector_type(4)));

__device__ __forceinline__ void bucket_of(int r, int& b, int& rl) {
    if (r < NTOT)          { int q = r / ADJ_RPB;               b = q;                rl = r - q * ADJ_RPB; }
    else if (r < HU_BASE)  { int rr = r - HV_BASE; int q = rr / HV_RPB;
                             b = NB_ADJ + q;                    rl = rr - q * HV_RPB; }
    else                   { int rr = r - HU_BASE; int q = rr / HU_RPB;
                             b = NB_ADJ + NB_HV + q;            rl = rr - q * HU_RPB; }
}

// ---------------------------------------------------------------------------
// Phase A: LDS-binned coarse scatter into fixed per-bucket slices of tmp[].
// tmp.x packs (rowLocal << 18) | col.  Tail: grid-stride fp32->fp16 convert.
// ---------------------------------------------------------------------------
__global__ void __launch_bounds__(PA_BLK)
phaseA_kernel(const int* __restrict__ adj_row, const int* __restrict__ adj_col,
              const float* __restrict__ adj_val,
              const int* __restrict__ hv_row, const int* __restrict__ hv_col,
              const float* __restrict__ hv_val,
              const int* __restrict__ hu_row, const int* __restrict__ hu_col,
              const float* __restrict__ hu_val,
              const float* __restrict__ user, const float* __restrict__ item,
              _Float16* __restrict__ x16,
              int* __restrict__ bkt_cnt, int2* __restrict__ tmp,
              int e_adj, int e_hv, int e_hu) {
    __shared__ int hist[HSIZE];
    __shared__ int lstart[HSIZE];
    __shared__ int destB[HSIZE];
    __shared__ int psum[HSIZE];
    __shared__ int2 stage[CHUNK];  // 64 KB

    const int tid = threadIdx.x;
    const int e_all = e_adj + e_hv + e_hu;
    const int base = blockIdx.x * CHUNK;
    const int nloc = min(CHUNK, e_all - base);

    if (tid < HSIZE) hist[tid] = 0;
    __syncthreads();

    for (int i = tid; i < nloc; i += PA_BLK) {
        int t = base + i, r;
        if (t < e_adj)             r = adj_row[t];
        else if (t < e_adj + e_hv) r = HV_BASE + hv_row[t - e_adj];
        else                       r = HU_BASE + hu_row[t - e_adj - e_hv];
        int b, rl; bucket_of(r, b, rl);
        atomicAdd(&hist[b], 1);
    }
    __syncthreads();

    int v = 0;
    if (tid < HSIZE) { v = hist[tid]; psum[tid] = v; }
    __syncthreads();
    for (int off = 1; off < HSIZE; off <<= 1) {
        int t = 0;
        if (tid < HSIZE && tid >= off) t = psum[tid - off];
        __syncthreads();
        if (tid < HSIZE) psum[tid] += t;
        __syncthreads();
    }
    if (tid < HSIZE) lstart[tid] = psum[tid] - v;
    __syncthreads();

    if (tid < NBKT) {
        int c = hist[tid];
        if (c > 0)
            destB[tid] = tid * EDGE_CAP + atomicAdd(&bkt_cnt[tid], c) - lstart[tid];
    }
    __syncthreads();
    if (tid < HSIZE) hist[tid] = lstart[tid];
    __syncthreads();

    for (int i = tid; i < nloc; i += PA_BLK) {
        int t = base + i, r, c; float v2;
        if (t < e_adj)             { r = adj_row[t]; c = adj_col[t]; v2 = adj_val[t]; }
        else if (t < e_adj + e_hv) { int k = t - e_adj;
                                     r = HV_BASE + hv_row[k]; c = hv_col[k]; v2 = hv_val[k]; }
        else                       { int k = t - e_adj - e_hv;
                                     r = HU_BASE + hu_row[k]; c = hu_col[k]; v2 = hu_val[k]; }
        int b, rl; bucket_of(r, b, rl);
        int p = atomicAdd(&hist[b], 1);
        stage[p] = make_int2(c | (rl << 18), __float_as_int(v2));
    }
    __syncthreads();

    const int wave = tid >> 6, lane = tid & 63;
    for (int b = wave; b < NBKT; b += (PA_BLK / 64)) {
        int s = lstart[b];
        int e = hist[b];
        int d = destB[b];
        for (int j = s + lane; j < e; j += 64)
            tmp[d + j] = stage[j];
    }

    // ---- folded fp32 -> fp16 conversion (independent of binning above) ----
    const int n8 = NTOT * DIM / 8;
    const int u8 = NUSERS * DIM / 8;
    const int gsz = gridDim.x * PA_BLK;
    for (int i = blockIdx.x * PA_BLK + tid; i < n8; i += gsz) {
        const float4* src = (i < u8) ? (const float4*)user + 2 * (size_t)i
                                     : (const float4*)item + 2 * (size_t)(i - u8);
        float4 a = src[0], b = src[1];
        h8 h;
        h[0] = (_Float16)a.x; h[1] = (_Float16)a.y; h[2] = (_Float16)a.z; h[3] = (_Float16)a.w;
        h[4] = (_Float16)b.x; h[5] = (_Float16)b.y; h[6] = (_Float16)b.z; h[7] = (_Float16)b.w;
        ((h8*)x16)[i] = h;
    }
}

// ---------------------------------------------------------------------------
// Phase B: per-block scan of bkt_cnt -> gbase, per-bucket row histogram +
// scan -> start[]/cnt[], counting sort -> CSR edges.  Natural row order.
// ---------------------------------------------------------------------------
__global__ void __launch_bounds__(PB_BLK)
phaseB_kernel(const int* __restrict__ bkt_cnt,
              const int2* __restrict__ tmp, int2* __restrict__ edges,
              int* __restrict__ start, int* __restrict__ cntArr) {
    __shared__ int  rh[ROWS_CAP];
    __shared__ int  rs[ROWS_CAP];
    __shared__ int  psum[PB_BLK];
    __shared__ int2 stage[EDGE_CAP];  // 40 KB

    const int tid = threadIdx.x;
    const int b = blockIdx.x;
    int rlo, nR;
    if (b < NB_ADJ)              { rlo = b * ADJ_RPB;                          nR = ADJ_RPB; }
    else if (b < NB_ADJ + NB_HV) { rlo = HV_BASE + (b - NB_ADJ) * HV_RPB;      nR = HV_RPB; }
    else                         { rlo = HU_BASE + (b - NB_ADJ - NB_HV) * HU_RPB; nR = HU_RPB; }

    const int nE = bkt_cnt[b];

    // block-local exclusive scan of all bucket counts -> this bucket's gbase
    int bv = (tid < NBKT) ? bkt_cnt[tid] : 0;
    psum[tid] = bv;
    __syncthreads();
    for (int off = 1; off < PB_BLK; off <<= 1) {
        int t = (tid >= off) ? psum[tid - off] : 0;
        __syncthreads();
        psum[tid] += t;
        __syncthreads();
    }
    const int gbase = psum[b] - nE;

    const int2* src = tmp + (size_t)b * EDGE_CAP;

    rh[tid] = 0;
    rh[tid + PB_BLK] = 0;
    __syncthreads();

    for (int i = tid; i < nE; i += PB_BLK) {
        int2 e = src[i];
        atomicAdd(&rh[((unsigned)e.x) >> 18], 1);
    }
    __syncthreads();

    // exclusive scan over ROWS_CAP=1024 entries, 2 per thread (psum reused)
    int a0 = rh[2 * tid], a1 = rh[2 * tid + 1];
    int tot = a0 + a1;
    psum[tid] = tot;
    __syncthreads();
    for (int off = 1; off < PB_BLK; off <<= 1) {
        int v = (tid >= off) ? psum[tid - off] : 0;
        __syncthreads();
        psum[tid] += v;
        __syncthreads();
    }
    int ex = psum[tid] - tot;
    rs[2 * tid]     = ex;
    rs[2 * tid + 1] = ex + a0;
    __syncthreads();

    // emit global CSR offsets
    for (int i = tid; i < nR; i += PB_BLK) {
        start[rlo + i]  = gbase + rs[i];
        cntArr[rlo + i] = rh[i];
    }
    __syncthreads();

    // counting sort into stage (rs doubles as cursor), then coalesced flush
    for (int i = tid; i < nE; i += PB_BLK) {
        int2 e = src[i];
        int rl = ((unsigned)e.x) >> 18;
        int p = atomicAdd(&rs[rl], 1);
        stage[p] = make_int2(e.x & 0x3FFFF, e.y);
    }
    __syncthreads();
    for (int i = tid; i < nE; i += PB_BLK) edges[gbase + i] = stage[i];
}

// ---------------------------------------------------------------------------
// Gather core: 8 lanes per row, 4-wide batches, software-pipelined —
// the NEXT edge batch is issued after the x-loads of the current batch are
// in flight and before they are consumed, so edge latency hides under
// x latency + FMA.  Edges read nontemporally as packed long long (read-once;
// keep L2 for the gather target).  Returns the row's value-sum (degree).
// ---------------------------------------------------------------------------
__device__ __forceinline__ float gather_row(const int2* __restrict__ edges,
                                            const _Float16* __restrict__ x,
                                            int s, int n, int c, float* acc) {
    const long long* ep = (const long long*)edges;
    float acc1[8] = {0.f, 0.f, 0.f, 0.f, 0.f, 0.f, 0.f, 0.f};
    float ds = 0.f;
    int j = s;
    const int e = s + n;
    long long e0, e1, e2, e3;
    if (j + 3 < e) {
        e0 = __builtin_nontemporal_load(ep + j);
        e1 = __builtin_nontemporal_load(ep + j + 1);
        e2 = __builtin_nontemporal_load(ep + j + 2);
        e3 = __builtin_nontemporal_load(ep + j + 3);
    }
    while (j + 3 < e) {
        float v0 = __int_as_float((int)(e0 >> 32));
        float v1 = __int_as_float((int)(e1 >> 32));
        float v2 = __int_as_float((int)(e2 >> 32));
        float v3 = __int_as_float((int)(e3 >> 32));
        int c0 = (int)(unsigned)e0, c1 = (int)(unsigned)e1;
        int c2 = (int)(unsigned)e2, c3 = (int)(unsigned)e3;
        // issue x loads for the current batch
        h8 x0 = *(const h8*)(x + (size_t)c0 * DIM + c);
        h8 x1 = *(const h8*)(x + (size_t)c1 * DIM + c);
        h8 x2 = *(const h8*)(x + (size_t)c2 * DIM + c);
        h8 x3 = *(const h8*)(x + (size_t)c3 * DIM + c);
        j += 4;
        // prefetch next edge batch while x loads are in flight
        if (j + 3 < e) {
            e0 = __builtin_nontemporal_load(ep + j);
            e1 = __builtin_nontemporal_load(ep + j + 1);
            e2 = __builtin_nontemporal_load(ep + j + 2);
            e3 = __builtin_nontemporal_load(ep + j + 3);
        }
        ds += (v0 + v1) + (v2 + v3);
        #pragma unroll
        for (int k = 0; k < 8; ++k) {
            acc[k]  += v0 * (float)x0[k] + v2 * (float)x2[k];
            acc1[k] += v1 * (float)x1[k] + v3 * (float)x3[k];
        }
    }
    for (; j < e; ++j) {
        long long ee = __builtin_nontemporal_load(ep + j);
        float v0 = __int_as_float((int)(ee >> 32));
        int c0 = (int)(unsigned)ee;
        h8 x0 = *(const h8*)(x + (size_t)c0 * DIM + c);
        ds += v0;
        #pragma unroll
        for (int k = 0; k < 8; ++k) acc[k] += v0 * (float)x0[k];
    }
    #pragma unroll
    for (int k = 0; k < 8; ++k) acc[k] += acc1[k];
    return ds;
}

// K1: layer1 (T0 = A*X16 over NTOT rows) + hv biclique (bic = norm(Hv*item16))
__global__ void gatherK1(const int* __restrict__ start, const int* __restrict__ cnt,
                         const int2* __restrict__ edges,
                         const _Float16* __restrict__ X16,
                         _Float16* __restrict__ T0, _Float16* __restrict__ bic,
                         int gA) {
    int c = (threadIdx.x & 7) << 3;
    int lrow = threadIdx.x >> 3;
    if (blockIdx.x < gA) {
        int r = blockIdx.x * 32 + lrow;
        if (r >= NTOT) return;
        float acc[8] = {0.f, 0.f, 0.f, 0.f, 0.f, 0.f, 0.f, 0.f};
        gather_row(edges, X16, start[r], cnt[r], c, acc);
        h8 o;
        #pragma unroll
        for (int k = 0; k < 8; ++k) o[k] = (_Float16)acc[k];
        __builtin_nontemporal_store(o, (h8*)(T0 + (size_t)r * DIM + c));
    } else {
        int g = (blockIdx.x - gA) * 32 + lrow;
        if (g >= NBIC) return;
        int r = HV_BASE + g;
        float acc[8] = {0.f, 0.f, 0.f, 0.f, 0.f, 0.f, 0.f, 0.f};
        float deg = gather_row(edges, X16 + (size_t)NUSERS * DIM, start[r], cnt[r], c, acc);
        if (deg == 0.f) deg = 1.f;
        float inv = 1.f / deg;
        h8 o;
        #pragma unroll
        for (int k = 0; k < 8; ++k) o[k] = (_Float16)(acc[k] * inv);
        __builtin_nontemporal_store(o, (h8*)(bic + (size_t)g * DIM + c));
    }
}

// K2: layer2 (T1 = A*T0) + hu (ulocal = norm(Hu*bic))
__global__ void gatherK2(const int* __restrict__ start, const int* __restrict__ cnt,
                         const int2* __restrict__ edges,
                         const _Float16* __restrict__ T0, const _Float16* __restrict__ bic,
                         _Float16* __restrict__ T1, _Float16* __restrict__ ulocal,
                         int gA) {
    int c = (threadIdx.x & 7) << 3;
    int lrow = threadIdx.x >> 3;
    if (blockIdx.x < gA) {
        int r = blockIdx.x * 32 + lrow;
        if (r >= NTOT) return;
        float acc[8] = {0.f, 0.f, 0.f, 0.f, 0.f, 0.f, 0.f, 0.f};
        gather_row(edges, T0, start[r], cnt[r], c, acc);
        h8 o;
        #pragma unroll
        for (int k = 0; k < 8; ++k) o[k] = (_Float16)acc[k];
        __builtin_nontemporal_store(o, (h8*)(T1 + (size_t)r * DIM + c));
    } else {
        int g = (blockIdx.x - gA) * 32 + lrow;
        if (g >= NUSERS) return;
        int r = HU_BASE + g;
        float acc[8] = {0.f, 0.f, 0.f, 0.f, 0.f, 0.f, 0.f, 0.f};
        float deg = gather_row(edges, bic, start[r], cnt[r], c, acc);
        if (deg == 0.f) deg = 1.f;
        float inv = 1.f / deg;
        h8 o;
        #pragma unroll
        for (int k = 0; k < 8; ++k) o[k] = (_Float16)(acc[k] * inv);
        __builtin_nontemporal_store(o, (h8*)(ulocal + (size_t)g * DIM + c));
    }
}

// K3: layer3 + epilogue: out = 0.25*(x0+t0+t1+gather(T1)) [+ ulocal users]
// Natural row order: epilogue reads and out writes stream (nontemporal, so
// L2 stays reserved for the random T1 gather).
__global__ void gatherK3(const int* __restrict__ start, const int* __restrict__ cnt,
                         const int2* __restrict__ edges,
                         const _Float16* __restrict__ X16,
                         const _Float16* __restrict__ T0,
                         const _Float16* __restrict__ T1,
                         const _Float16* __restrict__ ulocal,
                         float* __restrict__ out) {
    int r = blockIdx.x * 32 + (threadIdx.x >> 3);
    if (r >= NTOT) return;
    int c = (threadIdx.x & 7) << 3;
    float acc[8] = {0.f, 0.f, 0.f, 0.f, 0.f, 0.f, 0.f, 0.f};
    gather_row(edges, T1, start[r], cnt[r], c, acc);
    size_t o = (size_t)r * DIM + c;
    h8 x0 = __builtin_nontemporal_load((const h8*)(X16 + o));
    h8 t0 = __builtin_nontemporal_load((const h8*)(T0 + o));
    h8 t1 = __builtin_nontemporal_load((const h8*)(T1 + o));
    float rr[8];
    #pragma unroll
    for (int k = 0; k < 8; ++k)
        rr[k] = 0.25f * ((float)x0[k] + (float)t0[k] + (float)t1[k] + acc[k]);
    if (r < NUSERS) {
        h8 ul = __builtin_nontemporal_load((const h8*)(ulocal + o));
        #pragma unroll
        for (int k = 0; k < 8; ++k) rr[k] += (float)ul[k];
    }
    f4 lo = { rr[0], rr[1], rr[2], rr[3] };
    f4 hi = { rr[4], rr[5], rr[6], rr[7] };
    f4* op = (f4*)(out + o);
    __builtin_nontemporal_store(lo, op);
    __builtin_nontemporal_store(hi, op + 1);
}

// ---------------------------------------------------------------------------
extern "C" void kernel_launch(void* const* d_in, const int* in_sizes, int n_in,
                              void* d_out, int out_size, void* d_ws, size_t ws_size,
                              hipStream_t stream) {
    const float* user_emb = (const float*)d_in[0];
    const float* item_emb = (const float*)d_in[1];
    const float* adj_val  = (const float*)d_in[2];
    const float* hv_val   = (const float*)d_in[3];
    const float* hu_val   = (const float*)d_in[4];
    const int*   adj_row  = (const int*)d_in[5];
    const int*   adj_col  = (const int*)d_in[6];
    const int*   hv_row   = (const int*)d_in[7];
    const int*   hv_col   = (const int*)d_in[8];
    const int*   hu_row   = (const int*)d_in[9];
    const int*   hu_col   = (const int*)d_in[10];

    const int E_ADJ = in_sizes[2];
    const int E_HV  = in_sizes[3];
    const int E_HU  = in_sizes[4];
    const int E_ALL = E_ADJ + E_HV + E_HU;

    // -------- workspace carve-up (256B-aligned) --------
    char* ws = (char*)d_ws;
    auto alloc = [&](size_t bytes) -> char* {
        char* p = ws;
        ws += (bytes + 255) & ~(size_t)255;
        return p;
    };
    const size_t SZ_H = (size_t)NTOT * DIM * sizeof(_Float16);   // 19.2 MB
    _Float16* X16     = (_Float16*)alloc(SZ_H);
    _Float16* T0      = (_Float16*)alloc(SZ_H);
    _Float16* T1      = (_Float16*)alloc(SZ_H);
    _Float16* bic     = (_Float16*)alloc((size_t)NBIC * DIM * sizeof(_Float16));
    _Float16* ulocal  = (_Float16*)alloc((size_t)NUSERS * DIM * sizeof(_Float16));
    int*   cnt      = (int*)alloc((size_t)NROWS_ALL * sizeof(int));
    int*   start    = (int*)alloc((size_t)NROWS_ALL * sizeof(int));
    int2*  edges    = (int2*)alloc((size_t)E_ALL * sizeof(int2));
    int2*  tmp      = (int2*)alloc((size_t)NBKT * EDGE_CAP * sizeof(int2));  // 20.5 MB
    int*   bkt_cnt  = (int*)alloc(NBKT * sizeof(int));

    const int BLK = 256;
    auto cdiv = [](int a, int b) { return (a + b - 1) / b; };

    // ---- CSR build ----
    hipMemsetAsync(bkt_cnt, 0, NBKT * sizeof(int), stream);
    phaseA_kernel<<<cdiv(E_ALL, CHUNK), PA_BLK, 0, stream>>>(adj_row, adj_col, adj_val,
                                                             hv_row, hv_col, hv_val,
                                                             hu_row, hu_col, hu_val,
                                                             user_emb, item_emb, X16,
                                                             bkt_cnt, tmp, E_ADJ, E_HV, E_HU);
    phaseB_kernel<<<NBKT, PB_BLK, 0, stream>>>(bkt_cnt, tmp, edges, start, cnt);

    // ---- fused gathers (32 rows per 256-thread block, natural row order) ----
    const int gA  = cdiv(NTOT, 32);
    const int gHV = cdiv(NBIC, 32);
    const int gHU = cdiv(NUSERS, 32);

    gatherK1<<<gA + gHV, BLK, 0, stream>>>(start, cnt, edges, X16, T0, bic, gA);
    gatherK2<<<gA + gHU, BLK, 0, stream>>>(start, cnt, edges, T0, bic, T1, ulocal, gA);
    gatherK3<<<gA, BLK, 0, stream>>>(start, cnt, edges, X16, T0, T1, ulocal,
                                     (float*)d_out);
}

// Round 5
// 268.400 us; speedup vs baseline: 1.0037x; 1.0037x over previous
//
#include <hip/hip_runtime.h>

#define NUSERS 100000
#define NITEMS 50000
#define NTOT   150000   // NUSERS + NITEMS
#define NBIC   20000
#define DIM    64

// concatenated row space: [adj rows | hv rows | hu rows]
#define HV_BASE  NTOT
#define HU_BASE  (NTOT + NBIC)
#define NROWS_ALL (NTOT + NBIC + NUSERS)   // 270000

// static region-aware buckets: ~4000 expected edges per bucket
#define ADJ_RPB  500
#define NB_ADJ   300
#define HV_RPB   200
#define NB_HV    100
#define HU_RPB   1000
#define NB_HU    100
#define NBKT     (NB_ADJ + NB_HV + NB_HU)   // 500
#define HSIZE    512

#define EDGE_CAP 5120
#define ROWS_CAP 1024
#define CHUNK    8192
#define PA_BLK   1024
#define PB_BLK   512

typedef _Float16 h8 __attribute__((ext_vector_type(8)));
typedef float    f4 __attribute__((ext_vector_type(4)));

__device__ __forceinline__ void bucket_of(int r, int& b, int& rl) {
    if (r < NTOT)          { int q = r / ADJ_RPB;               b = q;                rl = r - q * ADJ_RPB; }
    else if (r < HU_BASE)  { int rr = r - HV_BASE; int q = rr / HV_RPB;
                             b = NB_ADJ + q;                    rl = rr - q * HV_RPB; }
    else                   { int rr = r - HU_BASE; int q = rr / HU_RPB;
                             b = NB_ADJ + NB_HV + q;            rl = rr - q * HU_RPB; }
}

// ---------------------------------------------------------------------------
// Phase A: LDS-binned coarse scatter into fixed per-bucket slices of tmp[].
// tmp.x packs (rowLocal << 18) | col.  Tail: grid-stride fp32->fp16 convert.
// ---------------------------------------------------------------------------
__global__ void __launch_bounds__(PA_BLK)
phaseA_kernel(const int* __restrict__ adj_row, const int* __restrict__ adj_col,
              const float* __restrict__ adj_val,
              const int* __restrict__ hv_row, const int* __restrict__ hv_col,
              const float* __restrict__ hv_val,
              const int* __restrict__ hu_row, const int* __restrict__ hu_col,
              const float* __restrict__ hu_val,
              const float* __restrict__ user, const float* __restrict__ item,
              _Float16* __restrict__ x16,
              int* __restrict__ bkt_cnt, int2* __restrict__ tmp,
              int e_adj, int e_hv, int e_hu) {
    __shared__ int hist[HSIZE];
    __shared__ int lstart[HSIZE];
    __shared__ int destB[HSIZE];
    __shared__ int psum[HSIZE];
    __shared__ int2 stage[CHUNK];  // 64 KB

    const int tid = threadIdx.x;
    const int e_all = e_adj + e_hv + e_hu;
    const int base = blockIdx.x * CHUNK;
    const int nloc = min(CHUNK, e_all - base);

    if (tid < HSIZE) hist[tid] = 0;
    __syncthreads();

    for (int i = tid; i < nloc; i += PA_BLK) {
        int t = base + i, r;
        if (t < e_adj)             r = adj_row[t];
        else if (t < e_adj + e_hv) r = HV_BASE + hv_row[t - e_adj];
        else                       r = HU_BASE + hu_row[t - e_adj - e_hv];
        int b, rl; bucket_of(r, b, rl);
        atomicAdd(&hist[b], 1);
    }
    __syncthreads();

    int v = 0;
    if (tid < HSIZE) { v = hist[tid]; psum[tid] = v; }
    __syncthreads();
    for (int off = 1; off < HSIZE; off <<= 1) {
        int t = 0;
        if (tid < HSIZE && tid >= off) t = psum[tid - off];
        __syncthreads();
        if (tid < HSIZE) psum[tid] += t;
        __syncthreads();
    }
    if (tid < HSIZE) lstart[tid] = psum[tid] - v;
    __syncthreads();

    if (tid < NBKT) {
        int c = hist[tid];
        if (c > 0)
            destB[tid] = tid * EDGE_CAP + atomicAdd(&bkt_cnt[tid], c) - lstart[tid];
    }
    __syncthreads();
    if (tid < HSIZE) hist[tid] = lstart[tid];
    __syncthreads();

    for (int i = tid; i < nloc; i += PA_BLK) {
        int t = base + i, r, c; float v2;
        if (t < e_adj)             { r = adj_row[t]; c = adj_col[t]; v2 = adj_val[t]; }
        else if (t < e_adj + e_hv) { int k = t - e_adj;
                                     r = HV_BASE + hv_row[k]; c = hv_col[k]; v2 = hv_val[k]; }
        else                       { int k = t - e_adj - e_hv;
                                     r = HU_BASE + hu_row[k]; c = hu_col[k]; v2 = hu_val[k]; }
        int b, rl; bucket_of(r, b, rl);
        int p = atomicAdd(&hist[b], 1);
        stage[p] = make_int2(c | (rl << 18), __float_as_int(v2));
    }
    __syncthreads();

    const int wave = tid >> 6, lane = tid & 63;
    for (int b = wave; b < NBKT; b += (PA_BLK / 64)) {
        int s = lstart[b];
        int e = hist[b];
        int d = destB[b];
        for (int j = s + lane; j < e; j += 64)
            tmp[d + j] = stage[j];
    }

    // ---- folded fp32 -> fp16 conversion (independent of binning above) ----
    const int n8 = NTOT * DIM / 8;
    const int u8 = NUSERS * DIM / 8;
    const int gsz = gridDim.x * PA_BLK;
    for (int i = blockIdx.x * PA_BLK + tid; i < n8; i += gsz) {
        const float4* src = (i < u8) ? (const float4*)user + 2 * (size_t)i
                                     : (const float4*)item + 2 * (size_t)(i - u8);
        float4 a = src[0], b = src[1];
        h8 h;
        h[0] = (_Float16)a.x; h[1] = (_Float16)a.y; h[2] = (_Float16)a.z; h[3] = (_Float16)a.w;
        h[4] = (_Float16)b.x; h[5] = (_Float16)b.y; h[6] = (_Float16)b.z; h[7] = (_Float16)b.w;
        ((h8*)x16)[i] = h;
    }
}

// ---------------------------------------------------------------------------
// Phase B: per-block scan of bkt_cnt -> gbase, per-bucket row histogram +
// scan -> start[]/cnt[], counting sort -> CSR edges.  Natural row order.
// ---------------------------------------------------------------------------
__global__ void __launch_bounds__(PB_BLK)
phaseB_kernel(const int* __restrict__ bkt_cnt,
              const int2* __restrict__ tmp, int2* __restrict__ edges,
              int* __restrict__ start, int* __restrict__ cntArr) {
    __shared__ int  rh[ROWS_CAP];
    __shared__ int  rs[ROWS_CAP];
    __shared__ int  psum[PB_BLK];
    __shared__ int2 stage[EDGE_CAP];  // 40 KB

    const int tid = threadIdx.x;
    const int b = blockIdx.x;
    int rlo, nR;
    if (b < NB_ADJ)              { rlo = b * ADJ_RPB;                          nR = ADJ_RPB; }
    else if (b < NB_ADJ + NB_HV) { rlo = HV_BASE + (b - NB_ADJ) * HV_RPB;      nR = HV_RPB; }
    else                         { rlo = HU_BASE + (b - NB_ADJ - NB_HV) * HU_RPB; nR = HU_RPB; }

    const int nE = bkt_cnt[b];

    // block-local exclusive scan of all bucket counts -> this bucket's gbase
    int bv = (tid < NBKT) ? bkt_cnt[tid] : 0;
    psum[tid] = bv;
    __syncthreads();
    for (int off = 1; off < PB_BLK; off <<= 1) {
        int t = (tid >= off) ? psum[tid - off] : 0;
        __syncthreads();
        psum[tid] += t;
        __syncthreads();
    }
    const int gbase = psum[b] - nE;

    const int2* src = tmp + (size_t)b * EDGE_CAP;

    rh[tid] = 0;
    rh[tid + PB_BLK] = 0;
    __syncthreads();

    for (int i = tid; i < nE; i += PB_BLK) {
        int2 e = src[i];
        atomicAdd(&rh[((unsigned)e.x) >> 18], 1);
    }
    __syncthreads();

    // exclusive scan over ROWS_CAP=1024 entries, 2 per thread (psum reused)
    int a0 = rh[2 * tid], a1 = rh[2 * tid + 1];
    int tot = a0 + a1;
    psum[tid] = tot;
    __syncthreads();
    for (int off = 1; off < PB_BLK; off <<= 1) {
        int v = (tid >= off) ? psum[tid - off] : 0;
        __syncthreads();
        psum[tid] += v;
        __syncthreads();
    }
    int ex = psum[tid] - tot;
    rs[2 * tid]     = ex;
    rs[2 * tid + 1] = ex + a0;
    __syncthreads();

    // emit global CSR offsets
    for (int i = tid; i < nR; i += PB_BLK) {
        start[rlo + i]  = gbase + rs[i];
        cntArr[rlo + i] = rh[i];
    }
    __syncthreads();

    // counting sort into stage (rs doubles as cursor), then coalesced flush
    for (int i = tid; i < nE; i += PB_BLK) {
        int2 e = src[i];
        int rl = ((unsigned)e.x) >> 18;
        int p = atomicAdd(&rs[rl], 1);
        stage[p] = make_int2(e.x & 0x3FFFF, e.y);
    }
    __syncthreads();
    for (int i = tid; i < nE; i += PB_BLK) edges[gbase + i] = stage[i];
}

// ---------------------------------------------------------------------------
// Gather core: 8 lanes per row, 4-wide batches, software-pipelined —
// the NEXT edge batch is issued after the x-loads of the current batch are
// in flight and before they are consumed.  Edges read nontemporally
// (read-once stream; keeps L2 lines for the gather target).  The x[] gather
// reads are PLAIN loads (L2-cached).  Returns the row's value-sum (degree).
// ---------------------------------------------------------------------------
__device__ __forceinline__ float gather_row(const int2* __restrict__ edges,
                                            const _Float16* __restrict__ x,
                                            int s, int n, int c, float* acc) {
    const long long* ep = (const long long*)edges;
    float acc1[8] = {0.f, 0.f, 0.f, 0.f, 0.f, 0.f, 0.f, 0.f};
    float ds = 0.f;
    int j = s;
    const int e = s + n;
    long long e0, e1, e2, e3;
    if (j + 3 < e) {
        e0 = __builtin_nontemporal_load(ep + j);
        e1 = __builtin_nontemporal_load(ep + j + 1);
        e2 = __builtin_nontemporal_load(ep + j + 2);
        e3 = __builtin_nontemporal_load(ep + j + 3);
    }
    while (j + 3 < e) {
        float v0 = __int_as_float((int)(e0 >> 32));
        float v1 = __int_as_float((int)(e1 >> 32));
        float v2 = __int_as_float((int)(e2 >> 32));
        float v3 = __int_as_float((int)(e3 >> 32));
        int c0 = (int)(unsigned)e0, c1 = (int)(unsigned)e1;
        int c2 = (int)(unsigned)e2, c3 = (int)(unsigned)e3;
        // issue x loads for the current batch (plain: L2-cached)
        h8 x0 = *(const h8*)(x + (size_t)c0 * DIM + c);
        h8 x1 = *(const h8*)(x + (size_t)c1 * DIM + c);
        h8 x2 = *(const h8*)(x + (size_t)c2 * DIM + c);
        h8 x3 = *(const h8*)(x + (size_t)c3 * DIM + c);
        j += 4;
        // prefetch next edge batch while x loads are in flight
        if (j + 3 < e) {
            e0 = __builtin_nontemporal_load(ep + j);
            e1 = __builtin_nontemporal_load(ep + j + 1);
            e2 = __builtin_nontemporal_load(ep + j + 2);
            e3 = __builtin_nontemporal_load(ep + j + 3);
        }
        ds += (v0 + v1) + (v2 + v3);
        #pragma unroll
        for (int k = 0; k < 8; ++k) {
            acc[k]  += v0 * (float)x0[k] + v2 * (float)x2[k];
            acc1[k] += v1 * (float)x1[k] + v3 * (float)x3[k];
        }
    }
    for (; j < e; ++j) {
        long long ee = __builtin_nontemporal_load(ep + j);
        float v0 = __int_as_float((int)(ee >> 32));
        int c0 = (int)(unsigned)ee;
        h8 x0 = *(const h8*)(x + (size_t)c0 * DIM + c);
        ds += v0;
        #pragma unroll
        for (int k = 0; k < 8; ++k) acc[k] += v0 * (float)x0[k];
    }
    #pragma unroll
    for (int k = 0; k < 8; ++k) acc[k] += acc1[k];
    return ds;
}

// K1: layer1 (T0 = A*X16 over NTOT rows) + hv biclique (bic = norm(Hv*item16))
// PLAIN stores: T0/bic are randomly gathered by the NEXT kernel -> keep in L2.
__global__ void gatherK1(const int* __restrict__ start, const int* __restrict__ cnt,
                         const int2* __restrict__ edges,
                         const _Float16* __restrict__ X16,
                         _Float16* __restrict__ T0, _Float16* __restrict__ bic,
                         int gA) {
    int c = (threadIdx.x & 7) << 3;
    int lrow = threadIdx.x >> 3;
    if (blockIdx.x < gA) {
        int r = blockIdx.x * 32 + lrow;
        if (r >= NTOT) return;
        float acc[8] = {0.f, 0.f, 0.f, 0.f, 0.f, 0.f, 0.f, 0.f};
        gather_row(edges, X16, start[r], cnt[r], c, acc);
        h8 o;
        #pragma unroll
        for (int k = 0; k < 8; ++k) o[k] = (_Float16)acc[k];
        *(h8*)(T0 + (size_t)r * DIM + c) = o;
    } else {
        int g = (blockIdx.x - gA) * 32 + lrow;
        if (g >= NBIC) return;
        int r = HV_BASE + g;
        float acc[8] = {0.f, 0.f, 0.f, 0.f, 0.f, 0.f, 0.f, 0.f};
        float deg = gather_row(edges, X16 + (size_t)NUSERS * DIM, start[r], cnt[r], c, acc);
        if (deg == 0.f) deg = 1.f;
        float inv = 1.f / deg;
        h8 o;
        #pragma unroll
        for (int k = 0; k < 8; ++k) o[k] = (_Float16)(acc[k] * inv);
        *(h8*)(bic + (size_t)g * DIM + c) = o;
    }
}

// K2: layer2 (T1 = A*T0) + hu (ulocal = norm(Hu*bic)).  PLAIN stores.
__global__ void gatherK2(const int* __restrict__ start, const int* __restrict__ cnt,
                         const int2* __restrict__ edges,
                         const _Float16* __restrict__ T0, const _Float16* __restrict__ bic,
                         _Float16* __restrict__ T1, _Float16* __restrict__ ulocal,
                         int gA) {
    int c = (threadIdx.x & 7) << 3;
    int lrow = threadIdx.x >> 3;
    if (blockIdx.x < gA) {
        int r = blockIdx.x * 32 + lrow;
        if (r >= NTOT) return;
        float acc[8] = {0.f, 0.f, 0.f, 0.f, 0.f, 0.f, 0.f, 0.f};
        gather_row(edges, T0, start[r], cnt[r], c, acc);
        h8 o;
        #pragma unroll
        for (int k = 0; k < 8; ++k) o[k] = (_Float16)acc[k];
        *(h8*)(T1 + (size_t)r * DIM + c) = o;
    } else {
        int g = (blockIdx.x - gA) * 32 + lrow;
        if (g >= NUSERS) return;
        int r = HU_BASE + g;
        float acc[8] = {0.f, 0.f, 0.f, 0.f, 0.f, 0.f, 0.f, 0.f};
        float deg = gather_row(edges, bic, start[r], cnt[r], c, acc);
        if (deg == 0.f) deg = 1.f;
        float inv = 1.f / deg;
        h8 o;
        #pragma unroll
        for (int k = 0; k < 8; ++k) o[k] = (_Float16)(acc[k] * inv);
        *(h8*)(ulocal + (size_t)g * DIM + c) = o;
    }
}

// K3: layer3 + epilogue: out = 0.25*(x0+t0+t1+gather(T1)) [+ ulocal users]
// Epilogue reads are last-use streams -> NT loads; out never re-read -> NT
// store.  T1 gather reads stay plain (L2 reuse from K2's stores).
__global__ void gatherK3(const int* __restrict__ start, const int* __restrict__ cnt,
                         const int2* __restrict__ edges,
                         const _Float16* __restrict__ X16,
                         const _Float16* __restrict__ T0,
                         const _Float16* __restrict__ T1,
                         const _Float16* __restrict__ ulocal,
                         float* __restrict__ out) {
    int r = blockIdx.x * 32 + (threadIdx.x >> 3);
    if (r >= NTOT) return;
    int c = (threadIdx.x & 7) << 3;
    float acc[8] = {0.f, 0.f, 0.f, 0.f, 0.f, 0.f, 0.f, 0.f};
    gather_row(edges, T1, start[r], cnt[r], c, acc);
    size_t o = (size_t)r * DIM + c;
    h8 x0 = __builtin_nontemporal_load((const h8*)(X16 + o));
    h8 t0 = __builtin_nontemporal_load((const h8*)(T0 + o));
    h8 t1 = __builtin_nontemporal_load((const h8*)(T1 + o));
    float rr[8];
    #pragma unroll
    for (int k = 0; k < 8; ++k)
        rr[k] = 0.25f * ((float)x0[k] + (float)t0[k] + (float)t1[k] + acc[k]);
    if (r < NUSERS) {
        h8 ul = __builtin_nontemporal_load((const h8*)(ulocal + o));
        #pragma unroll
        for (int k = 0; k < 8; ++k) rr[k] += (float)ul[k];
    }
    f4 lo = { rr[0], rr[1], rr[2], rr[3] };
    f4 hi = { rr[4], rr[5], rr[6], rr[7] };
    f4* op = (f4*)(out + o);
    __builtin_nontemporal_store(lo, op);
    __builtin_nontemporal_store(hi, op + 1);
}

// ---------------------------------------------------------------------------
extern "C" void kernel_launch(void* const* d_in, const int* in_sizes, int n_in,
                              void* d_out, int out_size, void* d_ws, size_t ws_size,
                              hipStream_t stream) {
    const float* user_emb = (const float*)d_in[0];
    const float* item_emb = (const float*)d_in[1];
    const float* adj_val  = (const float*)d_in[2];
    const float* hv_val   = (const float*)d_in[3];
    const float* hu_val   = (const float*)d_in[4];
    const int*   adj_row  = (const int*)d_in[5];
    const int*   adj_col  = (const int*)d_in[6];
    const int*   hv_row   = (const int*)d_in[7];
    const int*   hv_col   = (const int*)d_in[8];
    const int*   hu_row   = (const int*)d_in[9];
    const int*   hu_col   = (const int*)d_in[10];

    const int E_ADJ = in_sizes[2];
    const int E_HV  = in_sizes[3];
    const int E_HU  = in_sizes[4];
    const int E_ALL = E_ADJ + E_HV + E_HU;

    // -------- workspace carve-up (256B-aligned) --------
    char* ws = (char*)d_ws;
    auto alloc = [&](size_t bytes) -> char* {
        char* p = ws;
        ws += (bytes + 255) & ~(size_t)255;
        return p;
    };
    const size_t SZ_H = (size_t)NTOT * DIM * sizeof(_Float16);   // 19.2 MB
    _Float16* X16     = (_Float16*)alloc(SZ_H);
    _Float16* T0      = (_Float16*)alloc(SZ_H);
    _Float16* T1      = (_Float16*)alloc(SZ_H);
    _Float16* bic     = (_Float16*)alloc((size_t)NBIC * DIM * sizeof(_Float16));
    _Float16* ulocal  = (_Float16*)alloc((size_t)NUSERS * DIM * sizeof(_Float16));
    int*   cnt      = (int*)alloc((size_t)NROWS_ALL * sizeof(int));
    int*   start    = (int*)alloc((size_t)NROWS_ALL * sizeof(int));
    int2*  edges    = (int2*)alloc((size_t)E_ALL * sizeof(int2));
    int2*  tmp      = (int2*)alloc((size_t)NBKT * EDGE_CAP * sizeof(int2));  // 20.5 MB
    int*   bkt_cnt  = (int*)alloc(NBKT * sizeof(int));

    const int BLK = 256;
    auto cdiv = [](int a, int b) { return (a + b - 1) / b; };

    // ---- CSR build ----
    hipMemsetAsync(bkt_cnt, 0, NBKT * sizeof(int), stream);
    phaseA_kernel<<<cdiv(E_ALL, CHUNK), PA_BLK, 0, stream>>>(adj_row, adj_col, adj_val,
                                                             hv_row, hv_col, hv_val,
                                                             hu_row, hu_col, hu_val,
                                                             user_emb, item_emb, X16,
                                                             bkt_cnt, tmp, E_ADJ, E_HV, E_HU);
    phaseB_kernel<<<NBKT, PB_BLK, 0, stream>>>(bkt_cnt, tmp, edges, start, cnt);

    // ---- fused gathers (32 rows per 256-thread block, natural row order) ----
    const int gA  = cdiv(NTOT, 32);
    const int gHV = cdiv(NBIC, 32);
    const int gHU = cdiv(NUSERS, 32);

    gatherK1<<<gA + gHV, BLK, 0, stream>>>(start, cnt, edges, X16, T0, bic, gA);
    gatherK2<<<gA + gHU, BLK, 0, stream>>>(start, cnt, edges, T0, bic, T1, ulocal, gA);
    gatherK3<<<gA, BLK, 0, stream>>>(start, cnt, edges, X16, T0, T1, ulocal,
                                     (float*)d_out);
}

// Round 6
// 257.679 us; speedup vs baseline: 1.0455x; 1.0416x over previous
//
#include <hip/hip_runtime.h>

#define NUSERS 100000
#define NITEMS 50000
#define NTOT   150000   // NUSERS + NITEMS
#define NBIC   20000
#define DIM    64

// concatenated row space: [adj rows | hv rows | hu rows]
#define HV_BASE  NTOT
#define HU_BASE  (NTOT + NBIC)
#define NROWS_ALL (NTOT + NBIC + NUSERS)   // 270000

// static region-aware buckets: ~4000 expected edges per bucket
#define ADJ_RPB  500
#define NB_ADJ   300
#define HV_RPB   200
#define NB_HV    100
#define HU_RPB   1000
#define NB_HU    100
#define NBKT     (NB_ADJ + NB_HV + NB_HU)   // 500
#define HSIZE    512

#define EDGE_CAP 5120
#define ROWS_CAP 1024
#define CHUNK    2048      // was 8192: small chunks -> 977 blocks -> fills CUs
#define PA_BLK   512
#define PB_BLK   512

typedef _Float16 h8 __attribute__((ext_vector_type(8)));

__device__ __forceinline__ void bucket_of(int r, int& b, int& rl) {
    if (r < NTOT)          { int q = r / ADJ_RPB;               b = q;                rl = r - q * ADJ_RPB; }
    else if (r < HU_BASE)  { int rr = r - HV_BASE; int q = rr / HV_RPB;
                             b = NB_ADJ + q;                    rl = rr - q * HV_RPB; }
    else                   { int rr = r - HU_BASE; int q = rr / HU_RPB;
                             b = NB_ADJ + NB_HV + q;            rl = rr - q * HU_RPB; }
}

// ---------------------------------------------------------------------------
// Phase A: LDS-binned coarse scatter into fixed per-bucket slices of tmp[].
// tmp.x packs (rowLocal << 18) | col.  Tail: grid-stride fp32->fp16 convert.
// CHUNK=2048/PA_BLK=512: 24 KB LDS -> 4 blocks/CU, ~95% thread-slot fill.
// ---------------------------------------------------------------------------
__global__ void __launch_bounds__(PA_BLK)
phaseA_kernel(const int* __restrict__ adj_row, const int* __restrict__ adj_col,
              const float* __restrict__ adj_val,
              const int* __restrict__ hv_row, const int* __restrict__ hv_col,
              const float* __restrict__ hv_val,
              const int* __restrict__ hu_row, const int* __restrict__ hu_col,
              const float* __restrict__ hu_val,
              const float* __restrict__ user, const float* __restrict__ item,
              _Float16* __restrict__ x16,
              int* __restrict__ bkt_cnt, int2* __restrict__ tmp,
              int e_adj, int e_hv, int e_hu) {
    __shared__ int hist[HSIZE];
    __shared__ int lstart[HSIZE];
    __shared__ int destB[HSIZE];
    __shared__ int psum[HSIZE];
    __shared__ int2 stage[CHUNK];  // 16 KB

    const int tid = threadIdx.x;
    const int e_all = e_adj + e_hv + e_hu;
    const int base = blockIdx.x * CHUNK;
    const int nloc = min(CHUNK, e_all - base);

    hist[tid] = 0;
    __syncthreads();

    for (int i = tid; i < nloc; i += PA_BLK) {
        int t = base + i, r;
        if (t < e_adj)             r = adj_row[t];
        else if (t < e_adj + e_hv) r = HV_BASE + hv_row[t - e_adj];
        else                       r = HU_BASE + hu_row[t - e_adj - e_hv];
        int b, rl; bucket_of(r, b, rl);
        atomicAdd(&hist[b], 1);
    }
    __syncthreads();

    int v = hist[tid];
    psum[tid] = v;
    __syncthreads();
    for (int off = 1; off < HSIZE; off <<= 1) {
        int t = (tid >= off) ? psum[tid - off] : 0;
        __syncthreads();
        psum[tid] += t;
        __syncthreads();
    }
    lstart[tid] = psum[tid] - v;
    __syncthreads();

    if (tid < NBKT) {
        int c = hist[tid];
        if (c > 0)
            destB[tid] = tid * EDGE_CAP + atomicAdd(&bkt_cnt[tid], c) - lstart[tid];
    }
    __syncthreads();
    hist[tid] = lstart[tid];
    __syncthreads();

    for (int i = tid; i < nloc; i += PA_BLK) {
        int t = base + i, r, c; float v2;
        if (t < e_adj)             { r = adj_row[t]; c = adj_col[t]; v2 = adj_val[t]; }
        else if (t < e_adj + e_hv) { int k = t - e_adj;
                                     r = HV_BASE + hv_row[k]; c = hv_col[k]; v2 = hv_val[k]; }
        else                       { int k = t - e_adj - e_hv;
                                     r = HU_BASE + hu_row[k]; c = hu_col[k]; v2 = hu_val[k]; }
        int b, rl; bucket_of(r, b, rl);
        int p = atomicAdd(&hist[b], 1);
        stage[p] = make_int2(c | (rl << 18), __float_as_int(v2));
    }
    __syncthreads();

    const int wave = tid >> 6, lane = tid & 63;
    for (int b = wave; b < NBKT; b += (PA_BLK / 64)) {
        int s = lstart[b];
        int e = hist[b];
        int d = destB[b];
        for (int j = s + lane; j < e; j += 64)
            tmp[d + j] = stage[j];
    }

    // ---- folded fp32 -> fp16 conversion (independent of binning above) ----
    const int n8 = NTOT * DIM / 8;
    const int u8 = NUSERS * DIM / 8;
    const int gsz = gridDim.x * PA_BLK;
    for (int i = blockIdx.x * PA_BLK + tid; i < n8; i += gsz) {
        const float4* src = (i < u8) ? (const float4*)user + 2 * (size_t)i
                                     : (const float4*)item + 2 * (size_t)(i - u8);
        float4 a = src[0], b = src[1];
        h8 h;
        h[0] = (_Float16)a.x; h[1] = (_Float16)a.y; h[2] = (_Float16)a.z; h[3] = (_Float16)a.w;
        h[4] = (_Float16)b.x; h[5] = (_Float16)b.y; h[6] = (_Float16)b.z; h[7] = (_Float16)b.w;
        ((h8*)x16)[i] = h;
    }
}

// ---------------------------------------------------------------------------
// Phase B: per-bucket row histogram + scan -> start[]/cnt[], counting sort ->
// fixed-slice CSR edges (gbase = b*EDGE_CAP -> no cross-bucket scan needed).
// ---------------------------------------------------------------------------
__global__ void __launch_bounds__(PB_BLK)
phaseB_kernel(const int* __restrict__ bkt_cnt,
              const int2* __restrict__ tmp, int2* __restrict__ edges,
              int* __restrict__ start, int* __restrict__ cntArr) {
    __shared__ int  rh[ROWS_CAP];
    __shared__ int  rs[ROWS_CAP];
    __shared__ int  psum[PB_BLK];
    __shared__ int2 stage[EDGE_CAP];  // 40 KB

    const int tid = threadIdx.x;
    const int b = blockIdx.x;
    int rlo, nR;
    if (b < NB_ADJ)              { rlo = b * ADJ_RPB;                          nR = ADJ_RPB; }
    else if (b < NB_ADJ + NB_HV) { rlo = HV_BASE + (b - NB_ADJ) * HV_RPB;      nR = HV_RPB; }
    else                         { rlo = HU_BASE + (b - NB_ADJ - NB_HV) * HU_RPB; nR = HU_RPB; }

    const int nE = bkt_cnt[b];
    const int gbase = b * EDGE_CAP;          // fixed slice: no bucket scan
    const int2* src = tmp + (size_t)b * EDGE_CAP;

    rh[tid] = 0;
    rh[tid + PB_BLK] = 0;
    __syncthreads();

    for (int i = tid; i < nE; i += PB_BLK) {
        int2 e = src[i];
        atomicAdd(&rh[((unsigned)e.x) >> 18], 1);
    }
    __syncthreads();

    // exclusive scan over ROWS_CAP=1024 entries, 2 per thread
    int a0 = rh[2 * tid], a1 = rh[2 * tid + 1];
    int tot = a0 + a1;
    psum[tid] = tot;
    __syncthreads();
    for (int off = 1; off < PB_BLK; off <<= 1) {
        int v = (tid >= off) ? psum[tid - off] : 0;
        __syncthreads();
        psum[tid] += v;
        __syncthreads();
    }
    int ex = psum[tid] - tot;
    rs[2 * tid]     = ex;
    rs[2 * tid + 1] = ex + a0;
    __syncthreads();

    // emit global CSR offsets
    for (int i = tid; i < nR; i += PB_BLK) {
        start[rlo + i]  = gbase + rs[i];
        cntArr[rlo + i] = rh[i];
    }
    __syncthreads();

    // counting sort into stage (rs doubles as cursor), then coalesced flush
    for (int i = tid; i < nE; i += PB_BLK) {
        int2 e = src[i];
        int rl = ((unsigned)e.x) >> 18;
        int p = atomicAdd(&rs[rl], 1);
        stage[p] = make_int2(e.x & 0x3FFFF, e.y);
    }
    __syncthreads();
    for (int i = tid; i < nE; i += PB_BLK) edges[gbase + i] = stage[i];
}

// ---------------------------------------------------------------------------
// Gather core (round-1 exact): 8 lanes per row, 4-way unrolled edge loop,
// fp32 accumulate.  Returns the row's value-sum (degree).
// ---------------------------------------------------------------------------
__device__ __forceinline__ float gather_row(const int2* __restrict__ edges,
                                            const _Float16* __restrict__ x,
                                            int s, int n, int c, float* acc) {
    float acc1[8] = {0.f, 0.f, 0.f, 0.f, 0.f, 0.f, 0.f, 0.f};
    float ds = 0.f;
    int j = s, e = s + n;
    for (; j + 3 < e; j += 4) {
        int2 e0 = edges[j], e1 = edges[j + 1], e2 = edges[j + 2], e3 = edges[j + 3];
        float v0 = __int_as_float(e0.y), v1 = __int_as_float(e1.y);
        float v2 = __int_as_float(e2.y), v3 = __int_as_float(e3.y);
        h8 x0 = *(const h8*)(x + (size_t)e0.x * DIM + c);
        h8 x1 = *(const h8*)(x + (size_t)e1.x * DIM + c);
        h8 x2 = *(const h8*)(x + (size_t)e2.x * DIM + c);
        h8 x3 = *(const h8*)(x + (size_t)e3.x * DIM + c);
        ds += (v0 + v1) + (v2 + v3);
        #pragma unroll
        for (int k = 0; k < 8; ++k) {
            acc[k]  += v0 * (float)x0[k] + v2 * (float)x2[k];
            acc1[k] += v1 * (float)x1[k] + v3 * (float)x3[k];
        }
    }
    for (; j < e; ++j) {
        int2 e0 = edges[j];
        float v0 = __int_as_float(e0.y);
        h8 x0 = *(const h8*)(x + (size_t)e0.x * DIM + c);
        ds += v0;
        #pragma unroll
        for (int k = 0; k < 8; ++k) acc[k] += v0 * (float)x0[k];
    }
    #pragma unroll
    for (int k = 0; k < 8; ++k) acc[k] += acc1[k];
    return ds;
}

// K1: layer1 (T0 = A*X16 over NTOT rows) + hv biclique (bic = norm(Hv*item16))
__global__ void gatherK1(const int* __restrict__ start, const int* __restrict__ cnt,
                         const int2* __restrict__ edges,
                         const _Float16* __restrict__ X16,
                         _Float16* __restrict__ T0, _Float16* __restrict__ bic,
                         int gA) {
    int c = (threadIdx.x & 7) << 3;
    int lrow = threadIdx.x >> 3;
    if (blockIdx.x < gA) {
        int r = blockIdx.x * 32 + lrow;
        if (r >= NTOT) return;
        float acc[8] = {0.f, 0.f, 0.f, 0.f, 0.f, 0.f, 0.f, 0.f};
        gather_row(edges, X16, start[r], cnt[r], c, acc);
        h8 o;
        #pragma unroll
        for (int k = 0; k < 8; ++k) o[k] = (_Float16)acc[k];
        *(h8*)(T0 + (size_t)r * DIM + c) = o;
    } else {
        int g = (blockIdx.x - gA) * 32 + lrow;
        if (g >= NBIC) return;
        int r = HV_BASE + g;
        float acc[8] = {0.f, 0.f, 0.f, 0.f, 0.f, 0.f, 0.f, 0.f};
        float deg = gather_row(edges, X16 + (size_t)NUSERS * DIM, start[r], cnt[r], c, acc);
        if (deg == 0.f) deg = 1.f;
        float inv = 1.f / deg;
        h8 o;
        #pragma unroll
        for (int k = 0; k < 8; ++k) o[k] = (_Float16)(acc[k] * inv);
        *(h8*)(bic + (size_t)g * DIM + c) = o;
    }
}

// K2: layer2 (T1 = A*T0) + hu (ulocal = norm(Hu*bic))
__global__ void gatherK2(const int* __restrict__ start, const int* __restrict__ cnt,
                         const int2* __restrict__ edges,
                         const _Float16* __restrict__ T0, const _Float16* __restrict__ bic,
                         _Float16* __restrict__ T1, _Float16* __restrict__ ulocal,
                         int gA) {
    int c = (threadIdx.x & 7) << 3;
    int lrow = threadIdx.x >> 3;
    if (blockIdx.x < gA) {
        int r = blockIdx.x * 32 + lrow;
        if (r >= NTOT) return;
        float acc[8] = {0.f, 0.f, 0.f, 0.f, 0.f, 0.f, 0.f, 0.f};
        gather_row(edges, T0, start[r], cnt[r], c, acc);
        h8 o;
        #pragma unroll
        for (int k = 0; k < 8; ++k) o[k] = (_Float16)acc[k];
        *(h8*)(T1 + (size_t)r * DIM + c) = o;
    } else {
        int g = (blockIdx.x - gA) * 32 + lrow;
        if (g >= NUSERS) return;
        int r = HU_BASE + g;
        float acc[8] = {0.f, 0.f, 0.f, 0.f, 0.f, 0.f, 0.f, 0.f};
        float deg = gather_row(edges, bic, start[r], cnt[r], c, acc);
        if (deg == 0.f) deg = 1.f;
        float inv = 1.f / deg;
        h8 o;
        #pragma unroll
        for (int k = 0; k < 8; ++k) o[k] = (_Float16)(acc[k] * inv);
        *(h8*)(ulocal + (size_t)g * DIM + c) = o;
    }
}

// K3: layer3 + epilogue: out = 0.25*(x0+t0+t1+gather(T1)) [+ ulocal users]
__global__ void gatherK3(const int* __restrict__ start, const int* __restrict__ cnt,
                         const int2* __restrict__ edges,
                         const _Float16* __restrict__ X16,
                         const _Float16* __restrict__ T0,
                         const _Float16* __restrict__ T1,
                         const _Float16* __restrict__ ulocal,
                         float* __restrict__ out) {
    int r = blockIdx.x * 32 + (threadIdx.x >> 3);
    if (r >= NTOT) return;
    int c = (threadIdx.x & 7) << 3;
    float acc[8] = {0.f, 0.f, 0.f, 0.f, 0.f, 0.f, 0.f, 0.f};
    gather_row(edges, T1, start[r], cnt[r], c, acc);
    size_t o = (size_t)r * DIM + c;
    h8 x0 = *(const h8*)(X16 + o);
    h8 t0 = *(const h8*)(T0 + o);
    h8 t1 = *(const h8*)(T1 + o);
    float rr[8];
    #pragma unroll
    for (int k = 0; k < 8; ++k)
        rr[k] = 0.25f * ((float)x0[k] + (float)t0[k] + (float)t1[k] + acc[k]);
    if (r < NUSERS) {
        h8 ul = *(const h8*)(ulocal + o);
        #pragma unroll
        for (int k = 0; k < 8; ++k) rr[k] += (float)ul[k];
    }
    float4 lo = make_float4(rr[0], rr[1], rr[2], rr[3]);
    float4 hi = make_float4(rr[4], rr[5], rr[6], rr[7]);
    float4* op = (float4*)(out + o);
    op[0] = lo;
    op[1] = hi;
}

// ---------------------------------------------------------------------------
extern "C" void kernel_launch(void* const* d_in, const int* in_sizes, int n_in,
                              void* d_out, int out_size, void* d_ws, size_t ws_size,
                              hipStream_t stream) {
    const float* user_emb = (const float*)d_in[0];
    const float* item_emb = (const float*)d_in[1];
    const float* adj_val  = (const float*)d_in[2];
    const float* hv_val   = (const float*)d_in[3];
    const float* hu_val   = (const float*)d_in[4];
    const int*   adj_row  = (const int*)d_in[5];
    const int*   adj_col  = (const int*)d_in[6];
    const int*   hv_row   = (const int*)d_in[7];
    const int*   hv_col   = (const int*)d_in[8];
    const int*   hu_row   = (const int*)d_in[9];
    const int*   hu_col   = (const int*)d_in[10];

    const int E_ADJ = in_sizes[2];
    const int E_HV  = in_sizes[3];
    const int E_HU  = in_sizes[4];
    const int E_ALL = E_ADJ + E_HV + E_HU;

    // -------- workspace carve-up (256B-aligned) --------
    char* ws = (char*)d_ws;
    auto alloc = [&](size_t bytes) -> char* {
        char* p = ws;
        ws += (bytes + 255) & ~(size_t)255;
        return p;
    };
    const size_t SZ_H = (size_t)NTOT * DIM * sizeof(_Float16);   // 19.2 MB
    _Float16* X16     = (_Float16*)alloc(SZ_H);
    _Float16* T0      = (_Float16*)alloc(SZ_H);
    _Float16* T1      = (_Float16*)alloc(SZ_H);
    _Float16* bic     = (_Float16*)alloc((size_t)NBIC * DIM * sizeof(_Float16));
    _Float16* ulocal  = (_Float16*)alloc((size_t)NUSERS * DIM * sizeof(_Float16));
    int*   cnt      = (int*)alloc((size_t)NROWS_ALL * sizeof(int));
    int*   start    = (int*)alloc((size_t)NROWS_ALL * sizeof(int));
    int2*  edges    = (int2*)alloc((size_t)NBKT * EDGE_CAP * sizeof(int2));  // 20.5 MB (fixed slices)
    int2*  tmp      = (int2*)alloc((size_t)NBKT * EDGE_CAP * sizeof(int2));  // 20.5 MB
    int*   bkt_cnt  = (int*)alloc(NBKT * sizeof(int));

    const int BLK = 256;
    auto cdiv = [](int a, int b) { return (a + b - 1) / b; };

    // ---- CSR build ----
    hipMemsetAsync(bkt_cnt, 0, NBKT * sizeof(int), stream);
    phaseA_kernel<<<cdiv(E_ALL, CHUNK), PA_BLK, 0, stream>>>(adj_row, adj_col, adj_val,
                                                             hv_row, hv_col, hv_val,
                                                             hu_row, hu_col, hu_val,
                                                             user_emb, item_emb, X16,
                                                             bkt_cnt, tmp, E_ADJ, E_HV, E_HU);
    phaseB_kernel<<<NBKT, PB_BLK, 0, stream>>>(bkt_cnt, tmp, edges, start, cnt);

    // ---- fused gathers (32 rows per 256-thread block, natural row order) ----
    const int gA  = cdiv(NTOT, 32);
    const int gHV = cdiv(NBIC, 32);
    const int gHU = cdiv(NUSERS, 32);

    gatherK1<<<gA + gHV, BLK, 0, stream>>>(start, cnt, edges, X16, T0, bic, gA);
    gatherK2<<<gA + gHU, BLK, 0, stream>>>(start, cnt, edges, T0, bic, T1, ulocal, gA);
    gatherK3<<<gA, BLK, 0, stream>>>(start, cnt, edges, X16, T0, T1, ulocal,
                                     (float*)d_out);
}

// Round 7
// 252.328 us; speedup vs baseline: 1.0676x; 1.0212x over previous
//
#include <hip/hip_runtime.h>

#define NUSERS 100000
#define NITEMS 50000
#define NTOT   150000   // NUSERS + NITEMS
#define NBIC   20000
#define DIM    64

// concatenated row space: [adj rows | hv rows | hu rows]
#define HV_BASE  NTOT
#define HU_BASE  (NTOT + NBIC)
#define NROWS_ALL (NTOT + NBIC + NUSERS)   // 270000

// static region-aware buckets: ~4000 expected edges per bucket
#define ADJ_RPB  500
#define NB_ADJ   300
#define HV_RPB   200
#define NB_HV    100
#define HU_RPB   1000
#define NB_HU    100
#define NBKT     (NB_ADJ + NB_HV + NB_HU)   // 500
#define HSIZE    512

#define EDGE_CAP 5120
#define ROWS_CAP 1024
#define CHUNK    2048
#define PA_BLK   512
#define EPT      (CHUNK / PA_BLK)   // 4 edges per thread, held in registers
#define PB_BLK   512

typedef _Float16 h8 __attribute__((ext_vector_type(8)));

__device__ __forceinline__ void bucket_of(int r, int& b, int& rl) {
    if (r < NTOT)          { int q = r / ADJ_RPB;               b = q;                rl = r - q * ADJ_RPB; }
    else if (r < HU_BASE)  { int rr = r - HV_BASE; int q = rr / HV_RPB;
                             b = NB_ADJ + q;                    rl = rr - q * HV_RPB; }
    else                   { int rr = r - HU_BASE; int q = rr / HU_RPB;
                             b = NB_ADJ + NB_HV + q;            rl = rr - q * HU_RPB; }
}

// ---------------------------------------------------------------------------
// Phase A (register-resident rewrite): each thread owns EPT=4 edges in VGPRs.
// Pass 1 computes bucket + packed payload and builds the LDS histogram; the
// edge arrays are read from global exactly ONCE.  After the scan, placement
// records each staged element's bucket in sb[]; the flush is then fully
// dense: tmp[destB[sb[i]] + i] = stage[i] (all 64 lanes active, coalesced
// within buckets).  Tail: grid-stride fp32->fp16 convert.
// ---------------------------------------------------------------------------
__global__ void __launch_bounds__(PA_BLK)
phaseA_kernel(const int* __restrict__ adj_row, const int* __restrict__ adj_col,
              const float* __restrict__ adj_val,
              const int* __restrict__ hv_row, const int* __restrict__ hv_col,
              const float* __restrict__ hv_val,
              const int* __restrict__ hu_row, const int* __restrict__ hu_col,
              const float* __restrict__ hu_val,
              const float* __restrict__ user, const float* __restrict__ item,
              _Float16* __restrict__ x16,
              int* __restrict__ bkt_cnt, int2* __restrict__ tmp,
              int e_adj, int e_hv, int e_hu) {
    __shared__ int hist[HSIZE];
    __shared__ int cursor[HSIZE];
    __shared__ int destB[HSIZE];
    __shared__ int psum[HSIZE];
    __shared__ int2 stage[CHUNK];            // 16 KB
    __shared__ unsigned short sb[CHUNK];     // 4 KB

    const int tid = threadIdx.x;
    const int e_all = e_adj + e_hv + e_hu;
    const int base = blockIdx.x * CHUNK;
    const int nloc = min(CHUNK, e_all - base);

    hist[tid] = 0;
    __syncthreads();

    // ---- pass 1: edges -> registers, histogram ----
    int   rb[EPT];
    int   rpk[EPT];
    float rv[EPT];
    #pragma unroll
    for (int k = 0; k < EPT; ++k) {
        int i = tid + k * PA_BLK;
        rb[k] = -1;
        if (i < nloc) {
            int t = base + i, r, c; float v;
            if (t < e_adj)             { r = adj_row[t]; c = adj_col[t]; v = adj_val[t]; }
            else if (t < e_adj + e_hv) { int kk = t - e_adj;
                                         r = HV_BASE + hv_row[kk]; c = hv_col[kk]; v = hv_val[kk]; }
            else                       { int kk = t - e_adj - e_hv;
                                         r = HU_BASE + hu_row[kk]; c = hu_col[kk]; v = hu_val[kk]; }
            int b, rl; bucket_of(r, b, rl);
            rb[k]  = b;
            rpk[k] = c | (rl << 18);
            rv[k]  = v;
            atomicAdd(&hist[b], 1);
        }
    }
    __syncthreads();

    // ---- exclusive scan of hist (HSIZE == PA_BLK) ----
    int v = hist[tid];
    psum[tid] = v;
    __syncthreads();
    for (int off = 1; off < HSIZE; off <<= 1) {
        int t = (tid >= off) ? psum[tid - off] : 0;
        __syncthreads();
        psum[tid] += t;
        __syncthreads();
    }
    const int lst = psum[tid] - v;

    // ---- reserve global space per bucket ----
    if (tid < NBKT && v > 0)
        destB[tid] = tid * EDGE_CAP + atomicAdd(&bkt_cnt[tid], v) - lst;
    cursor[tid] = lst;
    __syncthreads();

    // ---- placement from registers into bucket-grouped stage ----
    #pragma unroll
    for (int k = 0; k < EPT; ++k) {
        if (rb[k] >= 0) {
            int p = atomicAdd(&cursor[rb[k]], 1);
            stage[p] = make_int2(rpk[k], __float_as_int(rv[k]));
            sb[p]    = (unsigned short)rb[k];
        }
    }
    __syncthreads();

    // ---- dense coalesced flush ----
    for (int i = tid; i < nloc; i += PA_BLK)
        tmp[destB[sb[i]] + i] = stage[i];

    // ---- folded fp32 -> fp16 conversion (independent of binning above) ----
    const int n8 = NTOT * DIM / 8;
    const int u8 = NUSERS * DIM / 8;
    const int gsz = gridDim.x * PA_BLK;
    for (int i = blockIdx.x * PA_BLK + tid; i < n8; i += gsz) {
        const float4* src = (i < u8) ? (const float4*)user + 2 * (size_t)i
                                     : (const float4*)item + 2 * (size_t)(i - u8);
        float4 a = src[0], b = src[1];
        h8 h;
        h[0] = (_Float16)a.x; h[1] = (_Float16)a.y; h[2] = (_Float16)a.z; h[3] = (_Float16)a.w;
        h[4] = (_Float16)b.x; h[5] = (_Float16)b.y; h[6] = (_Float16)b.z; h[7] = (_Float16)b.w;
        ((h8*)x16)[i] = h;
    }
}

// ---------------------------------------------------------------------------
// Phase B: per-bucket row histogram + scan -> start[]/cnt[], counting sort ->
// fixed-slice CSR edges (gbase = b*EDGE_CAP -> no cross-bucket scan needed).
// ---------------------------------------------------------------------------
__global__ void __launch_bounds__(PB_BLK)
phaseB_kernel(const int* __restrict__ bkt_cnt,
              const int2* __restrict__ tmp, int2* __restrict__ edges,
              int* __restrict__ start, int* __restrict__ cntArr) {
    __shared__ int  rh[ROWS_CAP];
    __shared__ int  rs[ROWS_CAP];
    __shared__ int  psum[PB_BLK];
    __shared__ int2 stage[EDGE_CAP];  // 40 KB

    const int tid = threadIdx.x;
    const int b = blockIdx.x;
    int rlo, nR;
    if (b < NB_ADJ)              { rlo = b * ADJ_RPB;                          nR = ADJ_RPB; }
    else if (b < NB_ADJ + NB_HV) { rlo = HV_BASE + (b - NB_ADJ) * HV_RPB;      nR = HV_RPB; }
    else                         { rlo = HU_BASE + (b - NB_ADJ - NB_HV) * HU_RPB; nR = HU_RPB; }

    const int nE = bkt_cnt[b];
    const int gbase = b * EDGE_CAP;          // fixed slice: no bucket scan
    const int2* src = tmp + (size_t)b * EDGE_CAP;

    rh[tid] = 0;
    rh[tid + PB_BLK] = 0;
    __syncthreads();

    for (int i = tid; i < nE; i += PB_BLK) {
        int2 e = src[i];
        atomicAdd(&rh[((unsigned)e.x) >> 18], 1);
    }
    __syncthreads();

    // exclusive scan over ROWS_CAP=1024 entries, 2 per thread
    int a0 = rh[2 * tid], a1 = rh[2 * tid + 1];
    int tot = a0 + a1;
    psum[tid] = tot;
    __syncthreads();
    for (int off = 1; off < PB_BLK; off <<= 1) {
        int v = (tid >= off) ? psum[tid - off] : 0;
        __syncthreads();
        psum[tid] += v;
        __syncthreads();
    }
    int ex = psum[tid] - tot;
    rs[2 * tid]     = ex;
    rs[2 * tid + 1] = ex + a0;
    __syncthreads();

    // emit global CSR offsets
    for (int i = tid; i < nR; i += PB_BLK) {
        start[rlo + i]  = gbase + rs[i];
        cntArr[rlo + i] = rh[i];
    }
    __syncthreads();

    // counting sort into stage (rs doubles as cursor), then coalesced flush
    for (int i = tid; i < nE; i += PB_BLK) {
        int2 e = src[i];
        int rl = ((unsigned)e.x) >> 18;
        int p = atomicAdd(&rs[rl], 1);
        stage[p] = make_int2(e.x & 0x3FFFF, e.y);
    }
    __syncthreads();
    for (int i = tid; i < nE; i += PB_BLK) edges[gbase + i] = stage[i];
}

// ---------------------------------------------------------------------------
// Gather core (round-1 exact): 8 lanes per row, 4-way unrolled edge loop,
// fp32 accumulate.  Returns the row's value-sum (degree).
// ---------------------------------------------------------------------------
__device__ __forceinline__ float gather_row(const int2* __restrict__ edges,
                                            const _Float16* __restrict__ x,
                                            int s, int n, int c, float* acc) {
    float acc1[8] = {0.f, 0.f, 0.f, 0.f, 0.f, 0.f, 0.f, 0.f};
    float ds = 0.f;
    int j = s, e = s + n;
    for (; j + 3 < e; j += 4) {
        int2 e0 = edges[j], e1 = edges[j + 1], e2 = edges[j + 2], e3 = edges[j + 3];
        float v0 = __int_as_float(e0.y), v1 = __int_as_float(e1.y);
        float v2 = __int_as_float(e2.y), v3 = __int_as_float(e3.y);
        h8 x0 = *(const h8*)(x + (size_t)e0.x * DIM + c);
        h8 x1 = *(const h8*)(x + (size_t)e1.x * DIM + c);
        h8 x2 = *(const h8*)(x + (size_t)e2.x * DIM + c);
        h8 x3 = *(const h8*)(x + (size_t)e3.x * DIM + c);
        ds += (v0 + v1) + (v2 + v3);
        #pragma unroll
        for (int k = 0; k < 8; ++k) {
            acc[k]  += v0 * (float)x0[k] + v2 * (float)x2[k];
            acc1[k] += v1 * (float)x1[k] + v3 * (float)x3[k];
        }
    }
    for (; j < e; ++j) {
        int2 e0 = edges[j];
        float v0 = __int_as_float(e0.y);
        h8 x0 = *(const h8*)(x + (size_t)e0.x * DIM + c);
        ds += v0;
        #pragma unroll
        for (int k = 0; k < 8; ++k) acc[k] += v0 * (float)x0[k];
    }
    #pragma unroll
    for (int k = 0; k < 8; ++k) acc[k] += acc1[k];
    return ds;
}

// K1: layer1 (T0 = A*X16 over NTOT rows) + hv biclique (bic = norm(Hv*item16))
__global__ void gatherK1(const int* __restrict__ start, const int* __restrict__ cnt,
                         const int2* __restrict__ edges,
                         const _Float16* __restrict__ X16,
                         _Float16* __restrict__ T0, _Float16* __restrict__ bic,
                         int gA) {
    int c = (threadIdx.x & 7) << 3;
    int lrow = threadIdx.x >> 3;
    if (blockIdx.x < gA) {
        int r = blockIdx.x * 32 + lrow;
        if (r >= NTOT) return;
        float acc[8] = {0.f, 0.f, 0.f, 0.f, 0.f, 0.f, 0.f, 0.f};
        gather_row(edges, X16, start[r], cnt[r], c, acc);
        h8 o;
        #pragma unroll
        for (int k = 0; k < 8; ++k) o[k] = (_Float16)acc[k];
        *(h8*)(T0 + (size_t)r * DIM + c) = o;
    } else {
        int g = (blockIdx.x - gA) * 32 + lrow;
        if (g >= NBIC) return;
        int r = HV_BASE + g;
        float acc[8] = {0.f, 0.f, 0.f, 0.f, 0.f, 0.f, 0.f, 0.f};
        float deg = gather_row(edges, X16 + (size_t)NUSERS * DIM, start[r], cnt[r], c, acc);
        if (deg == 0.f) deg = 1.f;
        float inv = 1.f / deg;
        h8 o;
        #pragma unroll
        for (int k = 0; k < 8; ++k) o[k] = (_Float16)(acc[k] * inv);
        *(h8*)(bic + (size_t)g * DIM + c) = o;
    }
}

// K2: layer2 (T1 = A*T0) + hu (ulocal = norm(Hu*bic))
__global__ void gatherK2(const int* __restrict__ start, const int* __restrict__ cnt,
                         const int2* __restrict__ edges,
                         const _Float16* __restrict__ T0, const _Float16* __restrict__ bic,
                         _Float16* __restrict__ T1, _Float16* __restrict__ ulocal,
                         int gA) {
    int c = (threadIdx.x & 7) << 3;
    int lrow = threadIdx.x >> 3;
    if (blockIdx.x < gA) {
        int r = blockIdx.x * 32 + lrow;
        if (r >= NTOT) return;
        float acc[8] = {0.f, 0.f, 0.f, 0.f, 0.f, 0.f, 0.f, 0.f};
        gather_row(edges, T0, start[r], cnt[r], c, acc);
        h8 o;
        #pragma unroll
        for (int k = 0; k < 8; ++k) o[k] = (_Float16)acc[k];
        *(h8*)(T1 + (size_t)r * DIM + c) = o;
    } else {
        int g = (blockIdx.x - gA) * 32 + lrow;
        if (g >= NUSERS) return;
        int r = HU_BASE + g;
        float acc[8] = {0.f, 0.f, 0.f, 0.f, 0.f, 0.f, 0.f, 0.f};
        float deg = gather_row(edges, bic, start[r], cnt[r], c, acc);
        if (deg == 0.f) deg = 1.f;
        float inv = 1.f / deg;
        h8 o;
        #pragma unroll
        for (int k = 0; k < 8; ++k) o[k] = (_Float16)(acc[k] * inv);
        *(h8*)(ulocal + (size_t)g * DIM + c) = o;
    }
}

// K3: layer3 + epilogue: out = 0.25*(x0+t0+t1+gather(T1)) [+ ulocal users]
__global__ void gatherK3(const int* __restrict__ start, const int* __restrict__ cnt,
                         const int2* __restrict__ edges,
                         const _Float16* __restrict__ X16,
                         const _Float16* __restrict__ T0,
                         const _Float16* __restrict__ T1,
                         const _Float16* __restrict__ ulocal,
                         float* __restrict__ out) {
    int r = blockIdx.x * 32 + (threadIdx.x >> 3);
    if (r >= NTOT) return;
    int c = (threadIdx.x & 7) << 3;
    float acc[8] = {0.f, 0.f, 0.f, 0.f, 0.f, 0.f, 0.f, 0.f};
    gather_row(edges, T1, start[r], cnt[r], c, acc);
    size_t o = (size_t)r * DIM + c;
    h8 x0 = *(const h8*)(X16 + o);
    h8 t0 = *(const h8*)(T0 + o);
    h8 t1 = *(const h8*)(T1 + o);
    float rr[8];
    #pragma unroll
    for (int k = 0; k < 8; ++k)
        rr[k] = 0.25f * ((float)x0[k] + (float)t0[k] + (float)t1[k] + acc[k]);
    if (r < NUSERS) {
        h8 ul = *(const h8*)(ulocal + o);
        #pragma unroll
        for (int k = 0; k < 8; ++k) rr[k] += (float)ul[k];
    }
    float4 lo = make_float4(rr[0], rr[1], rr[2], rr[3]);
    float4 hi = make_float4(rr[4], rr[5], rr[6], rr[7]);
    float4* op = (float4*)(out + o);
    op[0] = lo;
    op[1] = hi;
}

// ---------------------------------------------------------------------------
extern "C" void kernel_launch(void* const* d_in, const int* in_sizes, int n_in,
                              void* d_out, int out_size, void* d_ws, size_t ws_size,
                              hipStream_t stream) {
    const float* user_emb = (const float*)d_in[0];
    const float* item_emb = (const float*)d_in[1];
    const float* adj_val  = (const float*)d_in[2];
    const float* hv_val   = (const float*)d_in[3];
    const float* hu_val   = (const float*)d_in[4];
    const int*   adj_row  = (const int*)d_in[5];
    const int*   adj_col  = (const int*)d_in[6];
    const int*   hv_row   = (const int*)d_in[7];
    const int*   hv_col   = (const int*)d_in[8];
    const int*   hu_row   = (const int*)d_in[9];
    const int*   hu_col   = (const int*)d_in[10];

    const int E_ADJ = in_sizes[2];
    const int E_HV  = in_sizes[3];
    const int E_HU  = in_sizes[4];
    const int E_ALL = E_ADJ + E_HV + E_HU;

    // -------- workspace carve-up (256B-aligned) --------
    char* ws = (char*)d_ws;
    auto alloc = [&](size_t bytes) -> char* {
        char* p = ws;
        ws += (bytes + 255) & ~(size_t)255;
        return p;
    };
    const size_t SZ_H = (size_t)NTOT * DIM * sizeof(_Float16);   // 19.2 MB
    _Float16* X16     = (_Float16*)alloc(SZ_H);
    _Float16* T0      = (_Float16*)alloc(SZ_H);
    _Float16* T1      = (_Float16*)alloc(SZ_H);
    _Float16* bic     = (_Float16*)alloc((size_t)NBIC * DIM * sizeof(_Float16));
    _Float16* ulocal  = (_Float16*)alloc((size_t)NUSERS * DIM * sizeof(_Float16));
    int*   cnt      = (int*)alloc((size_t)NROWS_ALL * sizeof(int));
    int*   start    = (int*)alloc((size_t)NROWS_ALL * sizeof(int));
    int2*  edges    = (int2*)alloc((size_t)NBKT * EDGE_CAP * sizeof(int2));  // 20.5 MB (fixed slices)
    int2*  tmp      = (int2*)alloc((size_t)NBKT * EDGE_CAP * sizeof(int2));  // 20.5 MB
    int*   bkt_cnt  = (int*)alloc(NBKT * sizeof(int));

    const int BLK = 256;
    auto cdiv = [](int a, int b) { return (a + b - 1) / b; };

    // ---- CSR build ----
    hipMemsetAsync(bkt_cnt, 0, NBKT * sizeof(int), stream);
    phaseA_kernel<<<cdiv(E_ALL, CHUNK), PA_BLK, 0, stream>>>(adj_row, adj_col, adj_val,
                                                             hv_row, hv_col, hv_val,
                                                             hu_row, hu_col, hu_val,
                                                             user_emb, item_emb, X16,
                                                             bkt_cnt, tmp, E_ADJ, E_HV, E_HU);
    phaseB_kernel<<<NBKT, PB_BLK, 0, stream>>>(bkt_cnt, tmp, edges, start, cnt);

    // ---- fused gathers (32 rows per 256-thread block, natural row order) ----
    const int gA  = cdiv(NTOT, 32);
    const int gHV = cdiv(NBIC, 32);
    const int gHU = cdiv(NUSERS, 32);

    gatherK1<<<gA + gHV, BLK, 0, stream>>>(start, cnt, edges, X16, T0, bic, gA);
    gatherK2<<<gA + gHU, BLK, 0, stream>>>(start, cnt, edges, T0, bic, T1, ulocal, gA);
    gatherK3<<<gA, BLK, 0, stream>>>(start, cnt, edges, X16, T0, T1, ulocal,
                                     (float*)d_out);
}

// Round 8
// 248.528 us; speedup vs baseline: 1.0839x; 1.0153x over previous
//
#include <hip/hip_runtime.h>

#define NUSERS 100000
#define NITEMS 50000
#define NTOT   150000   // NUSERS + NITEMS
#define NBIC   20000
#define DIM    64

// concatenated row space: [adj rows | hv rows | hu rows]
#define HV_BASE  NTOT
#define HU_BASE  (NTOT + NBIC)
#define NROWS_ALL (NTOT + NBIC + NUSERS)   // 270000

// static region-aware buckets: ~4000 expected edges per bucket
#define ADJ_RPB  500
#define NB_ADJ   300
#define HV_RPB   200
#define NB_HV    100
#define HU_RPB   1000
#define NB_HU    100
#define NBKT     (NB_ADJ + NB_HV + NB_HU)   // 500
#define HSIZE    512

#define EDGE_CAP 5120
#define ROWS_CAP 1024
#define CHUNK    4096
#define PA_BLK   512
#define EPT      (CHUNK / PA_BLK)   // 8 edges per thread, held in registers
#define PB_BLK   512

typedef _Float16 h8 __attribute__((ext_vector_type(8)));

__device__ __forceinline__ void bucket_of(int r, int& b, int& rl) {
    if (r < NTOT)          { int q = r / ADJ_RPB;               b = q;                rl = r - q * ADJ_RPB; }
    else if (r < HU_BASE)  { int rr = r - HV_BASE; int q = rr / HV_RPB;
                             b = NB_ADJ + q;                    rl = rr - q * HV_RPB; }
    else                   { int rr = r - HU_BASE; int q = rr / HU_RPB;
                             b = NB_ADJ + NB_HV + q;            rl = rr - q * HU_RPB; }
}

// barrier-free wave inclusive scan (64 lanes)
__device__ __forceinline__ int wave_iscan(int v, int lane) {
    #pragma unroll
    for (int off = 1; off < 64; off <<= 1) {
        int t = __shfl_up(v, off, 64);
        if (lane >= off) v += t;
    }
    return v;
}

// ---------------------------------------------------------------------------
// Phase A (register-resident): each thread owns EPT=8 edges in VGPRs, edge
// arrays read from global exactly once.  Shuffle-based scan (2 barriers vs
// 18).  Dense coalesced flush via sb[] bucket tags.  Tail: fp32->fp16 conv.
// ---------------------------------------------------------------------------
__global__ void __launch_bounds__(PA_BLK)
phaseA_kernel(const int* __restrict__ adj_row, const int* __restrict__ adj_col,
              const float* __restrict__ adj_val,
              const int* __restrict__ hv_row, const int* __restrict__ hv_col,
              const float* __restrict__ hv_val,
              const int* __restrict__ hu_row, const int* __restrict__ hu_col,
              const float* __restrict__ hu_val,
              const float* __restrict__ user, const float* __restrict__ item,
              _Float16* __restrict__ x16,
              int* __restrict__ bkt_cnt, int2* __restrict__ tmp,
              int e_adj, int e_hv, int e_hu) {
    __shared__ int hist[HSIZE];
    __shared__ int cursor[HSIZE];
    __shared__ int destB[HSIZE];
    __shared__ int wsum[8];
    __shared__ int2 stage[CHUNK];            // 32 KB
    __shared__ unsigned short sb[CHUNK];     // 8 KB

    const int tid  = threadIdx.x;
    const int lane = tid & 63;
    const int wv   = tid >> 6;               // 8 waves
    const int e_all = e_adj + e_hv + e_hu;
    const int base = blockIdx.x * CHUNK;
    const int nloc = min(CHUNK, e_all - base);

    hist[tid] = 0;
    __syncthreads();

    // ---- pass 1: edges -> registers, histogram ----
    int   rb[EPT];
    int   rpk[EPT];
    float rv[EPT];
    #pragma unroll
    for (int k = 0; k < EPT; ++k) {
        int i = tid + k * PA_BLK;
        rb[k] = -1;
        if (i < nloc) {
            int t = base + i, r, c; float v;
            if (t < e_adj)             { r = adj_row[t]; c = adj_col[t]; v = adj_val[t]; }
            else if (t < e_adj + e_hv) { int kk = t - e_adj;
                                         r = HV_BASE + hv_row[kk]; c = hv_col[kk]; v = hv_val[kk]; }
            else                       { int kk = t - e_adj - e_hv;
                                         r = HU_BASE + hu_row[kk]; c = hu_col[kk]; v = hu_val[kk]; }
            int b, rl; bucket_of(r, b, rl);
            rb[k]  = b;
            rpk[k] = c | (rl << 18);
            rv[k]  = v;
            atomicAdd(&hist[b], 1);
        }
    }
    __syncthreads();

    // ---- shuffle-based exclusive scan of hist (HSIZE == PA_BLK) ----
    const int v   = hist[tid];
    int inc = wave_iscan(v, lane);
    if (lane == 63) wsum[wv] = inc;
    __syncthreads();
    if (wv == 0 && lane < 8) {
        int s0 = wsum[lane];
        int si = s0;
        #pragma unroll
        for (int off = 1; off < 8; off <<= 1) {
            int t = __shfl_up(si, off, 64);
            if (lane >= off) si += t;
        }
        wsum[lane] = si - s0;   // exclusive prefix of wave sums
    }
    __syncthreads();
    const int lst = inc - v + wsum[wv];      // block-exclusive prefix

    // ---- reserve global space per bucket ----
    if (tid < NBKT && v > 0)
        destB[tid] = tid * EDGE_CAP + atomicAdd(&bkt_cnt[tid], v) - lst;
    cursor[tid] = lst;
    __syncthreads();

    // ---- placement from registers into bucket-grouped stage ----
    #pragma unroll
    for (int k = 0; k < EPT; ++k) {
        if (rb[k] >= 0) {
            int p = atomicAdd(&cursor[rb[k]], 1);
            stage[p] = make_int2(rpk[k], __float_as_int(rv[k]));
            sb[p]    = (unsigned short)rb[k];
        }
    }
    __syncthreads();

    // ---- dense coalesced flush ----
    for (int i = tid; i < nloc; i += PA_BLK)
        tmp[destB[sb[i]] + i] = stage[i];

    // ---- folded fp32 -> fp16 conversion (independent of binning above) ----
    const int n8 = NTOT * DIM / 8;
    const int u8 = NUSERS * DIM / 8;
    const int gsz = gridDim.x * PA_BLK;
    for (int i = blockIdx.x * PA_BLK + tid; i < n8; i += gsz) {
        const float4* src = (i < u8) ? (const float4*)user + 2 * (size_t)i
                                     : (const float4*)item + 2 * (size_t)(i - u8);
        float4 a = src[0], b = src[1];
        h8 h;
        h[0] = (_Float16)a.x; h[1] = (_Float16)a.y; h[2] = (_Float16)a.z; h[3] = (_Float16)a.w;
        h[4] = (_Float16)b.x; h[5] = (_Float16)b.y; h[6] = (_Float16)b.z; h[7] = (_Float16)b.w;
        ((h8*)x16)[i] = h;
    }
}

// ---------------------------------------------------------------------------
// Phase B: per-bucket row histogram + shuffle-based scan -> start[]/cnt[],
// counting sort -> fixed-slice CSR edges (gbase = b*EDGE_CAP).
// ---------------------------------------------------------------------------
__global__ void __launch_bounds__(PB_BLK)
phaseB_kernel(const int* __restrict__ bkt_cnt,
              const int2* __restrict__ tmp, int2* __restrict__ edges,
              int* __restrict__ start, int* __restrict__ cntArr) {
    __shared__ int  rh[ROWS_CAP];
    __shared__ int  rs[ROWS_CAP];
    __shared__ int  wsum[8];
    __shared__ int2 stage[EDGE_CAP];  // 40 KB

    const int tid  = threadIdx.x;
    const int lane = tid & 63;
    const int wv   = tid >> 6;
    const int b = blockIdx.x;
    int rlo, nR;
    if (b < NB_ADJ)              { rlo = b * ADJ_RPB;                          nR = ADJ_RPB; }
    else if (b < NB_ADJ + NB_HV) { rlo = HV_BASE + (b - NB_ADJ) * HV_RPB;      nR = HV_RPB; }
    else                         { rlo = HU_BASE + (b - NB_ADJ - NB_HV) * HU_RPB; nR = HU_RPB; }

    const int nE = bkt_cnt[b];
    const int gbase = b * EDGE_CAP;          // fixed slice: no bucket scan
    const int2* src = tmp + (size_t)b * EDGE_CAP;

    rh[tid] = 0;
    rh[tid + PB_BLK] = 0;
    __syncthreads();

    for (int i = tid; i < nE; i += PB_BLK) {
        int2 e = src[i];
        atomicAdd(&rh[((unsigned)e.x) >> 18], 1);
    }
    __syncthreads();

    // ---- shuffle-based exclusive scan over ROWS_CAP=1024, 2 per thread ----
    const int a0 = rh[2 * tid], a1 = rh[2 * tid + 1];
    const int tot = a0 + a1;
    int inc = wave_iscan(tot, lane);
    if (lane == 63) wsum[wv] = inc;
    __syncthreads();
    if (wv == 0 && lane < 8) {
        int s0 = wsum[lane];
        int si = s0;
        #pragma unroll
        for (int off = 1; off < 8; off <<= 1) {
            int t = __shfl_up(si, off, 64);
            if (lane >= off) si += t;
        }
        wsum[lane] = si - s0;
    }
    __syncthreads();
    const int ex = inc - tot + wsum[wv];
    rs[2 * tid]     = ex;
    rs[2 * tid + 1] = ex + a0;
    __syncthreads();

    // emit global CSR offsets
    for (int i = tid; i < nR; i += PB_BLK) {
        start[rlo + i]  = gbase + rs[i];
        cntArr[rlo + i] = rh[i];
    }
    __syncthreads();

    // counting sort into stage (rs doubles as cursor), then coalesced flush
    for (int i = tid; i < nE; i += PB_BLK) {
        int2 e = src[i];
        int rl = ((unsigned)e.x) >> 18;
        int p = atomicAdd(&rs[rl], 1);
        stage[p] = make_int2(e.x & 0x3FFFF, e.y);
    }
    __syncthreads();
    for (int i = tid; i < nE; i += PB_BLK) edges[gbase + i] = stage[i];
}

// ---------------------------------------------------------------------------
// Gather core (round-1 exact): 8 lanes per row, 4-way unrolled edge loop,
// fp32 accumulate.  Returns the row's value-sum (degree).
// ---------------------------------------------------------------------------
__device__ __forceinline__ float gather_row(const int2* __restrict__ edges,
                                            const _Float16* __restrict__ x,
                                            int s, int n, int c, float* acc) {
    float acc1[8] = {0.f, 0.f, 0.f, 0.f, 0.f, 0.f, 0.f, 0.f};
    float ds = 0.f;
    int j = s, e = s + n;
    for (; j + 3 < e; j += 4) {
        int2 e0 = edges[j], e1 = edges[j + 1], e2 = edges[j + 2], e3 = edges[j + 3];
        float v0 = __int_as_float(e0.y), v1 = __int_as_float(e1.y);
        float v2 = __int_as_float(e2.y), v3 = __int_as_float(e3.y);
        h8 x0 = *(const h8*)(x + (size_t)e0.x * DIM + c);
        h8 x1 = *(const h8*)(x + (size_t)e1.x * DIM + c);
        h8 x2 = *(const h8*)(x + (size_t)e2.x * DIM + c);
        h8 x3 = *(const h8*)(x + (size_t)e3.x * DIM + c);
        ds += (v0 + v1) + (v2 + v3);
        #pragma unroll
        for (int k = 0; k < 8; ++k) {
            acc[k]  += v0 * (float)x0[k] + v2 * (float)x2[k];
            acc1[k] += v1 * (float)x1[k] + v3 * (float)x3[k];
        }
    }
    for (; j < e; ++j) {
        int2 e0 = edges[j];
        float v0 = __int_as_float(e0.y);
        h8 x0 = *(const h8*)(x + (size_t)e0.x * DIM + c);
        ds += v0;
        #pragma unroll
        for (int k = 0; k < 8; ++k) acc[k] += v0 * (float)x0[k];
    }
    #pragma unroll
    for (int k = 0; k < 8; ++k) acc[k] += acc1[k];
    return ds;
}

// K1: layer1 (T0 = A*X16 over NTOT rows) + hv biclique (bic = norm(Hv*item16))
__global__ void gatherK1(const int* __restrict__ start, const int* __restrict__ cnt,
                         const int2* __restrict__ edges,
                         const _Float16* __restrict__ X16,
                         _Float16* __restrict__ T0, _Float16* __restrict__ bic,
                         int gA) {
    int c = (threadIdx.x & 7) << 3;
    int lrow = threadIdx.x >> 3;
    if (blockIdx.x < gA) {
        int r = blockIdx.x * 32 + lrow;
        if (r >= NTOT) return;
        float acc[8] = {0.f, 0.f, 0.f, 0.f, 0.f, 0.f, 0.f, 0.f};
        gather_row(edges, X16, start[r], cnt[r], c, acc);
        h8 o;
        #pragma unroll
        for (int k = 0; k < 8; ++k) o[k] = (_Float16)acc[k];
        *(h8*)(T0 + (size_t)r * DIM + c) = o;
    } else {
        int g = (blockIdx.x - gA) * 32 + lrow;
        if (g >= NBIC) return;
        int r = HV_BASE + g;
        float acc[8] = {0.f, 0.f, 0.f, 0.f, 0.f, 0.f, 0.f, 0.f};
        float deg = gather_row(edges, X16 + (size_t)NUSERS * DIM, start[r], cnt[r], c, acc);
        if (deg == 0.f) deg = 1.f;
        float inv = 1.f / deg;
        h8 o;
        #pragma unroll
        for (int k = 0; k < 8; ++k) o[k] = (_Float16)(acc[k] * inv);
        *(h8*)(bic + (size_t)g * DIM + c) = o;
    }
}

// K2: layer2 (T1 = A*T0) + hu (ulocal = norm(Hu*bic))
__global__ void gatherK2(const int* __restrict__ start, const int* __restrict__ cnt,
                         const int2* __restrict__ edges,
                         const _Float16* __restrict__ T0, const _Float16* __restrict__ bic,
                         _Float16* __restrict__ T1, _Float16* __restrict__ ulocal,
                         int gA) {
    int c = (threadIdx.x & 7) << 3;
    int lrow = threadIdx.x >> 3;
    if (blockIdx.x < gA) {
        int r = blockIdx.x * 32 + lrow;
        if (r >= NTOT) return;
        float acc[8] = {0.f, 0.f, 0.f, 0.f, 0.f, 0.f, 0.f, 0.f};
        gather_row(edges, T0, start[r], cnt[r], c, acc);
        h8 o;
        #pragma unroll
        for (int k = 0; k < 8; ++k) o[k] = (_Float16)acc[k];
        *(h8*)(T1 + (size_t)r * DIM + c) = o;
    } else {
        int g = (blockIdx.x - gA) * 32 + lrow;
        if (g >= NUSERS) return;
        int r = HU_BASE + g;
        float acc[8] = {0.f, 0.f, 0.f, 0.f, 0.f, 0.f, 0.f, 0.f};
        float deg = gather_row(edges, bic, start[r], cnt[r], c, acc);
        if (deg == 0.f) deg = 1.f;
        float inv = 1.f / deg;
        h8 o;
        #pragma unroll
        for (int k = 0; k < 8; ++k) o[k] = (_Float16)(acc[k] * inv);
        *(h8*)(ulocal + (size_t)g * DIM + c) = o;
    }
}

// K3: layer3 + epilogue: out = 0.25*(x0+t0+t1+gather(T1)) [+ ulocal users]
__global__ void gatherK3(const int* __restrict__ start, const int* __restrict__ cnt,
                         const int2* __restrict__ edges,
                         const _Float16* __restrict__ X16,
                         const _Float16* __restrict__ T0,
                         const _Float16* __restrict__ T1,
                         const _Float16* __restrict__ ulocal,
                         float* __restrict__ out) {
    int r = blockIdx.x * 32 + (threadIdx.x >> 3);
    if (r >= NTOT) return;
    int c = (threadIdx.x & 7) << 3;
    float acc[8] = {0.f, 0.f, 0.f, 0.f, 0.f, 0.f, 0.f, 0.f};
    gather_row(edges, T1, start[r], cnt[r], c, acc);
    size_t o = (size_t)r * DIM + c;
    h8 x0 = *(const h8*)(X16 + o);
    h8 t0 = *(const h8*)(T0 + o);
    h8 t1 = *(const h8*)(T1 + o);
    float rr[8];
    #pragma unroll
    for (int k = 0; k < 8; ++k)
        rr[k] = 0.25f * ((float)x0[k] + (float)t0[k] + (float)t1[k] + acc[k]);
    if (r < NUSERS) {
        h8 ul = *(const h8*)(ulocal + o);
        #pragma unroll
        for (int k = 0; k < 8; ++k) rr[k] += (float)ul[k];
    }
    float4 lo = make_float4(rr[0], rr[1], rr[2], rr[3]);
    float4 hi = make_float4(rr[4], rr[5], rr[6], rr[7]);
    float4* op = (float4*)(out + o);
    op[0] = lo;
    op[1] = hi;
}

// ---------------------------------------------------------------------------
extern "C" void kernel_launch(void* const* d_in, const int* in_sizes, int n_in,
                              void* d_out, int out_size, void* d_ws, size_t ws_size,
                              hipStream_t stream) {
    const float* user_emb = (const float*)d_in[0];
    const float* item_emb = (const float*)d_in[1];
    const float* adj_val  = (const float*)d_in[2];
    const float* hv_val   = (const float*)d_in[3];
    const float* hu_val   = (const float*)d_in[4];
    const int*   adj_row  = (const int*)d_in[5];
    const int*   adj_col  = (const int*)d_in[6];
    const int*   hv_row   = (const int*)d_in[7];
    const int*   hv_col   = (const int*)d_in[8];
    const int*   hu_row   = (const int*)d_in[9];
    const int*   hu_col   = (const int*)d_in[10];

    const int E_ADJ = in_sizes[2];
    const int E_HV  = in_sizes[3];
    const int E_HU  = in_sizes[4];
    const int E_ALL = E_ADJ + E_HV + E_HU;

    // -------- workspace carve-up (256B-aligned) --------
    char* ws = (char*)d_ws;
    auto alloc = [&](size_t bytes) -> char* {
        char* p = ws;
        ws += (bytes + 255) & ~(size_t)255;
        return p;
    };
    const size_t SZ_H = (size_t)NTOT * DIM * sizeof(_Float16);   // 19.2 MB
    _Float16* X16     = (_Float16*)alloc(SZ_H);
    _Float16* T0      = (_Float16*)alloc(SZ_H);
    _Float16* T1      = (_Float16*)alloc(SZ_H);
    _Float16* bic     = (_Float16*)alloc((size_t)NBIC * DIM * sizeof(_Float16));
    _Float16* ulocal  = (_Float16*)alloc((size_t)NUSERS * DIM * sizeof(_Float16));
    int*   cnt      = (int*)alloc((size_t)NROWS_ALL * sizeof(int));
    int*   start    = (int*)alloc((size_t)NROWS_ALL * sizeof(int));
    int2*  edges    = (int2*)alloc((size_t)NBKT * EDGE_CAP * sizeof(int2));  // 20.5 MB (fixed slices)
    int2*  tmp      = (int2*)alloc((size_t)NBKT * EDGE_CAP * sizeof(int2));  // 20.5 MB
    int*   bkt_cnt  = (int*)alloc(NBKT * sizeof(int));

    const int BLK = 256;
    auto cdiv = [](int a, int b) { return (a + b - 1) / b; };

    // ---- CSR build ----
    hipMemsetAsync(bkt_cnt, 0, NBKT * sizeof(int), stream);
    phaseA_kernel<<<cdiv(E_ALL, CHUNK), PA_BLK, 0, stream>>>(adj_row, adj_col, adj_val,
                                                             hv_row, hv_col, hv_val,
                                                             hu_row, hu_col, hu_val,
                                                             user_emb, item_emb, X16,
                                                             bkt_cnt, tmp, E_ADJ, E_HV, E_HU);
    phaseB_kernel<<<NBKT, PB_BLK, 0, stream>>>(bkt_cnt, tmp, edges, start, cnt);

    // ---- fused gathers (32 rows per 256-thread block, natural row order) ----
    const int gA  = cdiv(NTOT, 32);
    const int gHV = cdiv(NBIC, 32);
    const int gHU = cdiv(NUSERS, 32);

    gatherK1<<<gA + gHV, BLK, 0, stream>>>(start, cnt, edges, X16, T0, bic, gA);
    gatherK2<<<gA + gHU, BLK, 0, stream>>>(start, cnt, edges, T0, bic, T1, ulocal, gA);
    gatherK3<<<gA, BLK, 0, stream>>>(start, cnt, edges, X16, T0, T1, ulocal,
                                     (float*)d_out);
}